// Round 1
// baseline (1658.080 us; speedup 1.0000x reference)
//
#include <hip/hip_runtime.h>
#include <math.h>

#define BNS 0.99999500003749981f  // 1/sqrt(1+1e-5)

// ---------------- 1x1 conv + bn + optional relu ----------------
// thread = one pixel, NCO output channels in registers; weight loads are
// wave-uniform -> scalar loads.
template<int NCO>
__global__ __launch_bounds__(256)
void conv1x1_bn(const float* __restrict__ in, const float* __restrict__ w,
                const float* __restrict__ g, const float* __restrict__ bb,
                float* __restrict__ out, int Bn, int CI, int CO, int HW, int relu)
{
    int p = blockIdx.x * 256 + threadIdx.x;
    int b = p / HW, pp = p - b * HW;
    int co0 = blockIdx.y * NCO;
    float acc[NCO];
#pragma unroll
    for (int k = 0; k < NCO; k++) acc[k] = 0.f;
    const float* ip = in + (size_t)b * CI * HW + pp;
    const float* wp = w + (size_t)co0 * CI;
#pragma unroll 4
    for (int ci = 0; ci < CI; ci++) {
        float xv = ip[(size_t)ci * HW];
#pragma unroll
        for (int k = 0; k < NCO; k++)
            acc[k] = fmaf(wp[(size_t)k * CI + ci], xv, acc[k]);
    }
#pragma unroll
    for (int k = 0; k < NCO; k++) {
        int co = co0 + k;
        if (co < CO) {
            float v = fmaf(acc[k], g[co] * BNS, bb[co]);
            if (relu) v = fmaxf(v, 0.f);
            out[((size_t)b * CO + co) * HW + pp] = v;
        }
    }
}

// ---------------- 3x3 conv (pad=1) + bn + optional relu ----------------
// Input may be a virtual concat of two NCHW tensors (inA: CIA ch, inB: CIB ch).
// thread = one output pixel, NCO output channels in registers.
// Border handling: clamped addresses + select-to-zero (branchless, no divergence).
template<int NCO>
__global__ __launch_bounds__(256)
void conv3x3_bn(const float* __restrict__ inA, int CIA,
                const float* __restrict__ inB, int CIB,
                const float* __restrict__ w,   // (CO, CIA+CIB, 3, 3)
                const float* __restrict__ g, const float* __restrict__ bb,
                float* __restrict__ out, int Bn, int CO, int H, int W, int relu)
{
    int HW = H * W;
    int p = blockIdx.x * 256 + threadIdx.x;
    int b = p / HW; int rem = p - b * HW;
    int y = rem / W; int x = rem - y * W;
    int CIT = CIA + CIB;
    int co0 = blockIdx.y * NCO;

    int roff[3] = { max(y - 1, 0) * W, y * W, min(y + 1, H - 1) * W };
    int coff[3] = { max(x - 1, 0),     x,     min(x + 1, W - 1)     };
    bool rv[3]  = { y > 0, true, y < H - 1 };
    bool cv[3]  = { x > 0, true, x < W - 1 };

    float acc[NCO];
#pragma unroll
    for (int k = 0; k < NCO; k++) acc[k] = 0.f;

    for (int s = 0; s < 2; s++) {
        const float* src = s ? inB : inA;
        int CI  = s ? CIB : CIA;
        int cw0 = s ? CIA : 0;
        if (CI == 0) continue;
        const float* base = src + (size_t)b * CI * HW;
        const float* wb   = w + ((size_t)co0 * CIT + cw0) * 9;
        for (int ci = 0; ci < CI; ci++) {
            const float* cb = base + (size_t)ci * HW;
            float v[9];
#pragma unroll
            for (int r = 0; r < 3; r++)
#pragma unroll
                for (int c = 0; c < 3; c++) {
                    float t = cb[roff[r] + coff[c]];
                    v[r * 3 + c] = (rv[r] && cv[c]) ? t : 0.f;
                }
            const float* wp = wb + (size_t)ci * 9;
#pragma unroll
            for (int k = 0; k < NCO; k++) {
                const float* wk = wp + (size_t)k * CIT * 9;
                float a = acc[k];
#pragma unroll
                for (int t = 0; t < 9; t++) a = fmaf(wk[t], v[t], a);
                acc[k] = a;
            }
        }
    }
#pragma unroll
    for (int k = 0; k < NCO; k++) {
        int co = co0 + k;
        if (co < CO) {
            float v = fmaf(acc[k], g[co] * BNS, bb[co]);
            if (relu) v = fmaxf(v, 0.f);
            out[((size_t)b * CO + co) * HW + rem] = v;
        }
    }
}

// ---------------- bilinear resize (align-corners linspace semantics) ----------------
__global__ __launch_bounds__(256)
void resize_ac2x(const float* __restrict__ in, float* __restrict__ out,
                 int BC, int Hi, int Wi, int Ho, int Wo)
{
    int idx = blockIdx.x * 256 + threadIdx.x;       // BC*Ho*Wo total, exact
    int wo = idx % Wo; int t = idx / Wo; int ho = t % Ho; int bc = t / Ho;
    float fy = (float)ho * (float)(Hi - 1) / (float)(Ho - 1);
    float fx = (float)wo * (float)(Wi - 1) / (float)(Wo - 1);
    int y0 = (int)fy; int x0 = (int)fx;             // fy,fx >= 0 -> trunc == floor
    float wy = fy - (float)y0, wx = fx - (float)x0;
    int y1 = min(y0 + 1, Hi - 1), x1 = min(x0 + 1, Wi - 1);
    const float* bp = in + (size_t)bc * Hi * Wi;
    float v00 = bp[y0 * Wi + x0], v01 = bp[y0 * Wi + x1];
    float v10 = bp[y1 * Wi + x0], v11 = bp[y1 * Wi + x1];
    float l = v00 * (1.f - wy) + v10 * wy;
    float r = v01 * (1.f - wy) + v11 * wy;
    out[idx] = l * (1.f - wx) + r * wx;
}

// ---------------- softmax over 25 channels (in-place) ----------------
__global__ __launch_bounds__(256)
void softmax25(float* __restrict__ wm, int Bn, int HW)
{
    int p = blockIdx.x * 256 + threadIdx.x;
    int b = p / HW, pp = p - b * HW;
    float* base = wm + (size_t)b * 25 * HW + pp;
    float v[25], m = -1e30f;
#pragma unroll
    for (int c = 0; c < 25; c++) { v[c] = base[(size_t)c * HW]; m = fmaxf(m, v[c]); }
    float s = 0.f;
#pragma unroll
    for (int c = 0; c < 25; c++) { v[c] = expf(v[c] - m); s += v[c]; }
    float inv = 1.f / s;
#pragma unroll
    for (int c = 0; c < 25; c++) base[(size_t)c * HW] = v[c] * inv;
}

// ---------------- CARAFE combine: X[b,c,y,x] = sum_ij Wm[b,5i+j,y,x]*xu[b,c,y+2i-4,x+2j-4]
// thread = one (b,y,x); 25 mask values held in registers across the 64-channel loop.
__global__ __launch_bounds__(256)
void carafe25(const float* __restrict__ wm, const float* __restrict__ xu,
              float* __restrict__ out, int Bn, int C, int Hq, int Wq)
{
    int p = blockIdx.x * 256 + threadIdx.x;
    int x = p % Wq; int t = p / Wq; int y = t % Hq; int b = t / Hq;
    int HW = Hq * Wq;
    const float* wmb = wm + (size_t)b * 25 * HW + y * Wq + x;
    float wv[25]; int off[25];
#pragma unroll
    for (int i = 0; i < 5; i++)
#pragma unroll
        for (int j = 0; j < 5; j++) {
            int tt = i * 5 + j;
            int yy = y + 2 * i - 4, xx = x + 2 * j - 4;
            bool ok = (yy >= 0) && (yy < Hq) && (xx >= 0) && (xx < Wq);
            float wvv = wmb[(size_t)tt * HW];
            wv[tt] = ok ? wvv : 0.f;
            int yc = min(max(yy, 0), Hq - 1), xc = min(max(xx, 0), Wq - 1);
            off[tt] = yc * Wq + xc;
        }
    const float* xb = xu + (size_t)b * C * HW;
    float* ob = out + (size_t)b * C * HW + y * Wq + x;
    for (int c = 0; c < C; c++) {
        const float* cb = xb + (size_t)c * HW;
        float a = 0.f;
#pragma unroll
        for (int tt = 0; tt < 25; tt++) a = fmaf(wv[tt], cb[off[tt]], a);
        ob[(size_t)c * HW] = a;
    }
}

// ---------------- final 1x1 conv 128->128 + bn + relu, IN-PLACE on d_out ----------------
// Block owns 64 pixels: stages all 128 input channels of those pixels in LDS,
// syncs, then computes & overwrites. No cross-block overlap -> race-free & deterministic.
__global__ __launch_bounds__(256)
void conv1x1_bn_inplace128(float* __restrict__ buf, const float* __restrict__ w,
                           const float* __restrict__ g, const float* __restrict__ bb,
                           int HW)
{
    constexpr int C = 128;
    __shared__ float tile[C][64];                  // 32 KB
    int pix0 = blockIdx.x * 64;
    int b = pix0 / HW; int pp0 = pix0 - b * HW;
    int tid = threadIdx.x;
    float* base = buf + (size_t)b * C * HW + pp0;
    for (int i = tid; i < C * 64; i += 256) {
        int ci = i >> 6, px = i & 63;
        tile[ci][px] = base[(size_t)ci * HW + px];
    }
    __syncthreads();
    int px = tid & 63, cg = tid >> 6;              // 4 co-groups of 32
    int co0 = cg * 32;
    float acc[32];
#pragma unroll
    for (int k = 0; k < 32; k++) acc[k] = 0.f;
    for (int ci = 0; ci < C; ci++) {
        float xv = tile[ci][px];
#pragma unroll
        for (int k = 0; k < 32; k++)
            acc[k] = fmaf(w[(size_t)(co0 + k) * C + ci], xv, acc[k]);
    }
#pragma unroll
    for (int k = 0; k < 32; k++) {
        int co = co0 + k;
        float v = fmaf(acc[k], g[co] * BNS, bb[co]);
        base[(size_t)co * HW + px] = fmaxf(v, 0.f);
    }
}

extern "C" void kernel_launch(void* const* d_in, const int* in_sizes, int n_in,
                              void* d_out, int out_size, void* d_ws, size_t ws_size,
                              hipStream_t stream)
{
    const float* x_h      = (const float*)d_in[0];
    const float* x_l      = (const float*)d_in[1];
    const float* w_reduce = (const float*)d_in[2];
    const float* g_reduce = (const float*)d_in[3];
    const float* b_reduce = (const float*)d_in[4];
    const float* w1       = (const float*)d_in[5];
    const float* g1       = (const float*)d_in[6];
    const float* b1       = (const float*)d_in[7];
    const float* w2       = (const float*)d_in[8];
    const float* g2       = (const float*)d_in[9];
    const float* b2       = (const float*)d_in[10];
    const float* w_enc    = (const float*)d_in[11];
    const float* g_enc    = (const float*)d_in[12];
    const float* b_enc    = (const float*)d_in[13];
    const float* w_out1   = (const float*)d_in[14];
    const float* g_out1   = (const float*)d_in[15];
    const float* b_out1   = (const float*)d_in[16];
    const float* w_out2   = (const float*)d_in[17];
    const float* g_out2   = (const float*)d_in[18];
    const float* b_out2   = (const float*)d_in[19];

    constexpr int B = 4, CH = 256, CL = 128, Hs = 64, Ws = 64, Ho = 128, Wo = 128;
    constexpr int CMID = 64, IC = 64, COF = 128;
    constexpr int HWs = Hs * Ws;    // 4096
    constexpr int HWo = Ho * Wo;    // 16384

    // workspace layout (f32 elements); total 44.3 MB, every buffer fully
    // rewritten each call before being read -> graph-replay deterministic.
    float* ws  = (float*)d_ws;
    float* c1  = ws;                                  // (4,64,64,64)
    float* x1  = c1 + (size_t)B * CMID * HWs;         // (4,64,128,128)
    float* x2  = x1 + (size_t)B * CMID * HWo;         // (4,64,128,128)
    float* wmb = x2 + (size_t)B * CMID * HWo;         // (4,25,128,128)
    float* xr  = c1;                                  // reuse (c1 dead after step 2)
    float* xu  = x1;                                  // reuse (x1 dead after step 4)
    float* Xb  = x2;                                  // reuse (x2 dead after step 4)
    float* y1  = (float*)d_out;                       // y1 lives in d_out

    // 1) c1 = cbr(x_h, w1)            1x1: 256->64 @64x64
    conv1x1_bn<8><<<dim3(B * HWs / 256, CMID / 8), 256, 0, stream>>>(
        x_h, w1, g1, b1, c1, B, CH, CMID, HWs, 1);
    // 2) x1 = resize(c1) -> 128x128
    resize_ac2x<<<(B * CMID * HWo) / 256, 256, 0, stream>>>(
        c1, x1, B * CMID, Hs, Ws, Ho, Wo);
    // 3) x2 = cbr(x_l, w2)            1x1: 128->64 @128x128
    conv1x1_bn<8><<<dim3(B * HWo / 256, CMID / 8), 256, 0, stream>>>(
        x_l, w2, g2, b2, x2, B, CL, CMID, HWo, 1);
    // 4) wm = conv3x3(concat(x1,x2), w_enc), pad=1, no relu: 128->25
    conv3x3_bn<8><<<dim3(B * HWo / 256, (25 + 7) / 8), 256, 0, stream>>>(
        x1, CMID, x2, CMID, w_enc, g_enc, b_enc, wmb, B, 25, Ho, Wo, 0);
    // 5) softmax over the 25 mask channels
    softmax25<<<(B * HWo) / 256, 256, 0, stream>>>(wmb, B, HWo);
    // 6) xr = cbr3x3(x_h, w_reduce)   3x3: 256->64 @64x64
    conv3x3_bn<8><<<dim3(B * HWs / 256, IC / 8), 256, 0, stream>>>(
        x_h, CH, x_h, 0, w_reduce, g_reduce, b_reduce, xr, B, IC, Hs, Ws, 1);
    // 7) xu = resize(xr) -> 128x128
    resize_ac2x<<<(B * IC * HWo) / 256, 256, 0, stream>>>(
        xr, xu, B * IC, Hs, Ws, Ho, Wo);
    // 8) X = carafe(wm, xu)
    carafe25<<<(B * HWo) / 256, 256, 0, stream>>>(wmb, xu, Xb, B, IC, Ho, Wo);
    // 9) y1 = cbr3x3(concat(X, x_l), w_out1)  3x3: 192->128 @128x128  -> d_out
    conv3x3_bn<8><<<dim3(B * HWo / 256, COF / 8), 256, 0, stream>>>(
        Xb, IC, x_l, CL, w_out1, g_out1, b_out1, y1, B, COF, Ho, Wo, 1);
    // 10) out = cbr1x1(y1, w_out2) in place on d_out
    conv1x1_bn_inplace128<<<(B * HWo) / 64, 256, 0, stream>>>(
        y1, w_out2, g_out2, b_out2, HWo);
}

// Round 2
// 316.649 us; speedup vs baseline: 5.2363x; 5.2363x over previous
//
#include <hip/hip_runtime.h>
#include <math.h>

#define BNS 0.99999500003749981f  // 1/sqrt(1+1e-5)

typedef short          bf16x8  __attribute__((ext_vector_type(8)));
typedef float          f32x4   __attribute__((ext_vector_type(4)));
typedef unsigned short u16x8   __attribute__((ext_vector_type(8)));
typedef unsigned short u16x4   __attribute__((ext_vector_type(4)));
typedef unsigned short ushort_t;

__device__ inline ushort_t f2b(float f) {
    union { float f; unsigned int u; } x; x.f = f;
    unsigned int u = x.u;
    unsigned int r = (u + 0x7FFFu + ((u >> 16) & 1u)) >> 16;   // RNE
    return (ushort_t)r;
}
__device__ inline float b2f(ushort_t s) {
    union { unsigned int u; float f; } x; x.u = ((unsigned int)s) << 16;
    return x.f;
}

// ============================================================================
// Weight prep: OIHW f32 -> [tap][co][ci] bf16 (MFMA A-operand friendly:
// lane reads 8 consecutive ci at row co). enc is zero-padded co 25..31.
// ============================================================================
__device__ inline void wseg(int lidx, const float* src, ushort_t* dst,
                            int TAPS, int CO, int CIT, int CO_real) {
    int tap = lidx / (CO * CIT);
    int r   = lidx - tap * (CO * CIT);
    int co  = r / CIT;
    int ci  = r - co * CIT;
    float v = (co < CO_real) ? src[(size_t)(co * CIT + ci) * TAPS + tap] : 0.f;
    dst[((size_t)tap * CO + co) * CIT + ci] = f2b(v);
}

__global__ __launch_bounds__(256)
void prep_weights(const float* wr, const float* w1, const float* w2,
                  const float* we, const float* wo1, const float* wo2,
                  ushort_t* br, ushort_t* b1, ushort_t* b2,
                  ushort_t* be, ushort_t* bo1, ushort_t* bo2)
{
    int idx = blockIdx.x * 256 + threadIdx.x;
    // segment sizes
    const int n0 = 9*64*256;    // reduce   147456
    const int n1 = 64*256;      // w1        16384
    const int n2 = 64*128;      // w2         8192
    const int n3 = 9*32*128;    // enc       36864 (src co 25)
    const int n4 = 9*128*192;   // out1     221184
    const int n5 = 128*128;     // out2      16384
    if (idx < n0) { wseg(idx, wr, br, 9, 64, 256, 64); return; } idx -= n0;
    if (idx < n1) { wseg(idx, w1, b1, 1, 64, 256, 64); return; } idx -= n1;
    if (idx < n2) { wseg(idx, w2, b2, 1, 64, 128, 64); return; } idx -= n2;
    if (idx < n3) { wseg(idx, we, be, 9, 32, 128, 25); return; } idx -= n3;
    if (idx < n4) { wseg(idx, wo1, bo1, 9, 128, 192, 128); return; } idx -= n4;
    if (idx < n5) { wseg(idx, wo2, bo2, 1, 128, 128, 128); return; }
}

// ============================================================================
// NCHW f32 -> NHWC bf16.  thread = one pixel; c-loop reads are coalesced
// across the wave (consecutive lanes = consecutive px); 16B vector stores.
// ============================================================================
__global__ __launch_bounds__(256)
void nchw2nhwc(const float* __restrict__ in, ushort_t* __restrict__ out,
               int C, int LHW, int npx)
{
    int px = blockIdx.x * 256 + threadIdx.x;
    if (px >= npx) return;
    int HW = 1 << LHW;
    int b = px >> LHW, phw = px & (HW - 1);
    const float* src = in + (size_t)b * C * HW + phw;
    ushort_t* dst = out + (size_t)px * C;
    for (int c0 = 0; c0 < C; c0 += 8) {
        u16x8 o;
#pragma unroll
        for (int j = 0; j < 8; j++) o[j] = f2b(src[(size_t)(c0 + j) * HW]);
        *reinterpret_cast<u16x8*>(dst + c0) = o;
    }
}

// ============================================================================
// Implicit-GEMM conv, bf16 MFMA 16x16x32.
//  A-operand = weights  [tap][co][ciT]   (lane&15 = co row, 8 consecutive ci)
//  B-operand = NHWC act (lane&15 = px col, 8 consecutive ci)
//  D frag: col(l&15)=px, row((l>>4)*4+r)=co -> 4 consecutive co per lane.
// Two activation sources = channel concat. TAPS in {1,9}. EPI 0: NHWC bf16,
// EPI 1: NCHW f32 (final output). px-split two-pointer I/O for halved bufs.
// ============================================================================
template<int TAPS, int MF, int NF, int EPI>
__global__ __launch_bounds__(256)
void conv_mfma(const ushort_t* __restrict__ srcA, int ldA, int ciA,
               const ushort_t* __restrict__ srcA2, int mSplitA,
               const ushort_t* __restrict__ srcB, int ldB, int ciB,
               const ushort_t* __restrict__ bw, int COt, int CIT,
               const float* __restrict__ g, const float* __restrict__ bia,
               int COclamp,
               void* __restrict__ outp, void* __restrict__ outp2, int mSplitO,
               int ldo, int LW, int H, int Mtot, int LHW, int relu)
{
    const int lane = threadIdx.x & 63;
    const int wid  = threadIdx.x >> 6;
    const int l15  = lane & 15, lhi = lane >> 4;
    const int px0_blk = blockIdx.x * (64 * MF);
    const int px0 = px0_blk + wid * (MF * 16);
    const int co_base = blockIdx.y * (NF * 16);
    const int khi8 = lhi * 8;
    const int W = 1 << LW;

    const ushort_t* sA = srcA; int mbias = 0;
    if (srcA2 && px0_blk >= mSplitA) { sA = srcA2; mbias = mSplitA; }

    int m_[MF], ym[MF], xm[MF];
#pragma unroll
    for (int mf = 0; mf < MF; ++mf) {
        m_[mf] = px0 + mf * 16 + l15;
        ym[mf] = (m_[mf] >> LW) & (H - 1);
        xm[mf] = m_[mf] & (W - 1);
    }

    f32x4 acc[NF][MF];
#pragma unroll
    for (int nf = 0; nf < NF; nf++)
#pragma unroll
        for (int mf = 0; mf < MF; mf++)
            acc[nf][mf] = (f32x4){0.f, 0.f, 0.f, 0.f};

    const ushort_t* wbase[NF];
#pragma unroll
    for (int nf = 0; nf < NF; ++nf)
        wbase[nf] = bw + (size_t)(co_base + nf * 16 + l15) * CIT + khi8;
    const size_t tapStride = (size_t)COt * CIT;
    const bf16x8 vz = {0, 0, 0, 0, 0, 0, 0, 0};
    const int NT = (TAPS == 9) ? 9 : 1;

#pragma unroll 1
    for (int s = 0; s < 2; ++s) {
        const ushort_t* act = s ? srcB : sA;
        if (!act) continue;
        const int ld   = s ? ldB : ldA;
        const int nkc  = (s ? ciB : ciA) >> 5;
        const int cio0 = s ? ciA : 0;
        const int mb   = s ? 0 : mbias;
#pragma unroll 1
        for (int tap = 0; tap < NT; ++tap) {
            const int dy = (TAPS == 9) ? tap / 3 - 1 : 0;
            const int dx = (TAPS == 9) ? tap % 3 - 1 : 0;
            size_t rowb[MF]; bool okm[MF];
#pragma unroll
            for (int mf = 0; mf < MF; ++mf) {
                bool ok = true;
                int mm = m_[mf];
                if (TAPS == 9) {
                    int yy = ym[mf] + dy, xx = xm[mf] + dx;
                    ok = (yy >= 0) & (yy < H) & (xx >= 0) & (xx < W);
                    mm = mm + dy * W + dx;
                    mm = min(max(mm, 0), Mtot - 1);
                }
                okm[mf]  = ok;
                rowb[mf] = (size_t)(mm - mb) * ld + khi8;
            }
            const size_t toff = (size_t)tap * tapStride + cio0;
            for (int kc = 0; kc < nkc; ++kc) {
                const int cio = kc * 32;
                bf16x8 bv[MF];
#pragma unroll
                for (int mf = 0; mf < MF; ++mf) {
                    bf16x8 v = *reinterpret_cast<const bf16x8*>(act + rowb[mf] + cio);
                    if (!okm[mf]) v = vz;
                    bv[mf] = v;
                }
                bf16x8 wv[NF];
#pragma unroll
                for (int nf = 0; nf < NF; ++nf)
                    wv[nf] = *reinterpret_cast<const bf16x8*>(wbase[nf] + toff + cio);
#pragma unroll
                for (int nf = 0; nf < NF; ++nf)
#pragma unroll
                    for (int mf = 0; mf < MF; ++mf)
                        acc[nf][mf] = __builtin_amdgcn_mfma_f32_16x16x32_bf16(
                            wv[nf], bv[mf], acc[nf][mf], 0, 0, 0);
            }
        }
    }

    // ---------------- epilogue ----------------
    const int cob = co_base + (lhi << 2);
    if (EPI == 0) {
        ushort_t* o1 = (ushort_t*)outp; int ob = 0;
        if (outp2 && px0_blk >= mSplitO) { o1 = (ushort_t*)outp2; ob = mSplitO; }
#pragma unroll
        for (int nf = 0; nf < NF; ++nf) {
            float sc[4], bi[4];
#pragma unroll
            for (int r = 0; r < 4; r++) {
                int c = min(cob + nf * 16 + r, COclamp - 1);
                sc[r] = g[c] * BNS; bi[r] = bia[c];
            }
#pragma unroll
            for (int mf = 0; mf < MF; ++mf) {
                f32x4 a = acc[nf][mf];
                u16x4 ov;
#pragma unroll
                for (int r = 0; r < 4; r++) {
                    float v = fmaf(a[r], sc[r], bi[r]);
                    if (relu) v = fmaxf(v, 0.f);
                    ov[r] = f2b(v);
                }
                int px = px0 + mf * 16 + l15;
                *reinterpret_cast<u16x4*>(
                    o1 + (size_t)(px - ob) * ldo + co_base + nf * 16 + (lhi << 2)) = ov;
            }
        }
    } else {
        float* o1 = (float*)outp;
        const int HW = 1 << LHW;
#pragma unroll
        for (int nf = 0; nf < NF; ++nf) {
            float sc[4], bi[4];
#pragma unroll
            for (int r = 0; r < 4; r++) {
                int c = min(cob + nf * 16 + r, COclamp - 1);
                sc[r] = g[c] * BNS; bi[r] = bia[c];
            }
#pragma unroll
            for (int mf = 0; mf < MF; ++mf) {
                int px = px0 + mf * 16 + l15;
                int b = px >> LHW, phw = px & (HW - 1);
#pragma unroll
                for (int r = 0; r < 4; r++) {
                    float v = fmaf(acc[nf][mf][r], sc[r], bi[r]);
                    if (relu) v = fmaxf(v, 0.f);
                    o1[((size_t)(b * COt + cob + nf * 16 + r)) * HW + phw] = v;
                }
            }
        }
    }
}

// ============================================================================
// 2x bilinear resize (align-corners linspace), NHWC bf16, C=64.
// thread = (opx, 8-channel group)
// ============================================================================
__global__ __launch_bounds__(256)
void resize2x_nhwc(const ushort_t* __restrict__ in, ushort_t* __restrict__ out,
                   int Hi, int Wi, int Ho, int Wo, int C)
{
    int t = blockIdx.x * 256 + threadIdx.x;
    int cg = t & 7;                 // C/8 == 8
    int opx = t >> 3;
    int Wmask = Wo - 1;
    int xo = opx & Wmask;
    int rest = opx >> 7;            // log2(Wo)=7
    int yo = rest & (Ho - 1);
    int b  = rest >> 7;             // log2(Ho)=7
    float fy = (float)yo * (float)(Hi - 1) / (float)(Ho - 1);
    float fx = (float)xo * (float)(Wi - 1) / (float)(Wo - 1);
    int y0 = (int)fy, x0 = (int)fx;
    float wy = fy - (float)y0, wx = fx - (float)x0;
    int y1 = min(y0 + 1, Hi - 1), x1 = min(x0 + 1, Wi - 1);
    size_t base = ((size_t)b * Hi) * Wi;
    const bf16x8* p00 = reinterpret_cast<const bf16x8*>(in + ((base + (size_t)y0 * Wi + x0) * C) + cg * 8);
    const bf16x8* p01 = reinterpret_cast<const bf16x8*>(in + ((base + (size_t)y0 * Wi + x1) * C) + cg * 8);
    const bf16x8* p10 = reinterpret_cast<const bf16x8*>(in + ((base + (size_t)y1 * Wi + x0) * C) + cg * 8);
    const bf16x8* p11 = reinterpret_cast<const bf16x8*>(in + ((base + (size_t)y1 * Wi + x1) * C) + cg * 8);
    bf16x8 v00 = *p00, v01 = *p01, v10 = *p10, v11 = *p11;
    u16x8 o;
#pragma unroll
    for (int k = 0; k < 8; k++) {
        float l = b2f((ushort_t)v00[k]) * (1.f - wy) + b2f((ushort_t)v10[k]) * wy;
        float r = b2f((ushort_t)v01[k]) * (1.f - wy) + b2f((ushort_t)v11[k]) * wy;
        o[k] = f2b(l * (1.f - wx) + r * wx);
    }
    *reinterpret_cast<u16x8*>(out + (size_t)opx * C + cg * 8) = o;
}

// ============================================================================
// softmax over 25 channels, NHWC stride 32 bf16, in place
// ============================================================================
__global__ __launch_bounds__(256)
void softmax25(ushort_t* __restrict__ wm, int npx)
{
    int px = blockIdx.x * 256 + threadIdx.x;
    if (px >= npx) return;
    ushort_t* p = wm + (size_t)px * 32;
    u16x8 r0 = *reinterpret_cast<u16x8*>(p);
    u16x8 r1 = *reinterpret_cast<u16x8*>(p + 8);
    u16x8 r2 = *reinterpret_cast<u16x8*>(p + 16);
    u16x8 r3 = *reinterpret_cast<u16x8*>(p + 24);
    float v[25];
#pragma unroll
    for (int k = 0; k < 8; k++) v[k]      = b2f(r0[k]);
#pragma unroll
    for (int k = 0; k < 8; k++) v[8 + k]  = b2f(r1[k]);
#pragma unroll
    for (int k = 0; k < 8; k++) v[16 + k] = b2f(r2[k]);
    v[24] = b2f(r3[0]);
    float m = v[0];
#pragma unroll
    for (int c = 1; c < 25; c++) m = fmaxf(m, v[c]);
    float s = 0.f;
#pragma unroll
    for (int c = 0; c < 25; c++) { v[c] = __expf(v[c] - m); s += v[c]; }
    float inv = 1.f / s;
#pragma unroll
    for (int c = 0; c < 25; c++) p[c] = f2b(v[c] * inv);
}

// ============================================================================
// CARAFE combine: X[px, c] = sum_ij wm[px, 5i+j] * xu[px + (2i-4)*W + (2j-4), c]
// NHWC bf16; thread = (px, 8-channel group), C=64, H=W=128.
// ============================================================================
__global__ __launch_bounds__(256)
void carafe25(const ushort_t* __restrict__ wm, const ushort_t* __restrict__ xu,
              ushort_t* __restrict__ out)
{
    int t = blockIdx.x * 256 + threadIdx.x;
    int cg = t & 7;
    int px = t >> 3;
    int x = px & 127;
    int y = (px >> 7) & 127;
    const ushort_t* wp = wm + (size_t)px * 32;
    float acc[8];
#pragma unroll
    for (int k = 0; k < 8; k++) acc[k] = 0.f;
#pragma unroll 1
    for (int i = 0; i < 5; i++) {
        int yy = y + 2 * i - 4;
        if (yy < 0 || yy > 127) continue;
#pragma unroll
        for (int j = 0; j < 5; j++) {
            int xx = x + 2 * j - 4;
            if (xx < 0 || xx > 127) continue;
            float wv = b2f(wp[i * 5 + j]);
            int q = px + (2 * i - 4) * 128 + (2 * j - 4);
            bf16x8 xv = *reinterpret_cast<const bf16x8*>(xu + (size_t)q * 64 + cg * 8);
#pragma unroll
            for (int k = 0; k < 8; k++)
                acc[k] = fmaf(wv, b2f((ushort_t)xv[k]), acc[k]);
        }
    }
    u16x8 o;
#pragma unroll
    for (int k = 0; k < 8; k++) o[k] = f2b(acc[k]);
    *reinterpret_cast<u16x8*>(out + (size_t)px * 64 + cg * 8) = o;
}

// ============================================================================
extern "C" void kernel_launch(void* const* d_in, const int* in_sizes, int n_in,
                              void* d_out, int out_size, void* d_ws, size_t ws_size,
                              hipStream_t stream)
{
    const float* x_h      = (const float*)d_in[0];
    const float* x_l      = (const float*)d_in[1];
    const float* w_reduce = (const float*)d_in[2];
    const float* g_reduce = (const float*)d_in[3];
    const float* b_reduce = (const float*)d_in[4];
    const float* w1       = (const float*)d_in[5];
    const float* g1       = (const float*)d_in[6];
    const float* b1       = (const float*)d_in[7];
    const float* w2       = (const float*)d_in[8];
    const float* g2       = (const float*)d_in[9];
    const float* b2       = (const float*)d_in[10];
    const float* w_enc    = (const float*)d_in[11];
    const float* g_enc    = (const float*)d_in[12];
    const float* b_enc    = (const float*)d_in[13];
    const float* w_out1   = (const float*)d_in[14];
    const float* g_out1   = (const float*)d_in[15];
    const float* b_out1   = (const float*)d_in[16];
    const float* w_out2   = (const float*)d_in[17];
    const float* g_out2   = (const float*)d_in[18];
    const float* b_out2   = (const float*)d_in[19];

    char* wsb = (char*)d_ws;
    // bf16 weight buffers  [tap][co][ci]
    ushort_t* BWr  = (ushort_t*)(wsb + 0);        // 147456 el
    ushort_t* BW1  = (ushort_t*)(wsb + 294912);   //  16384
    ushort_t* BW2  = (ushort_t*)(wsb + 327680);   //   8192
    ushort_t* BWe  = (ushort_t*)(wsb + 344064);   //  36864
    ushort_t* BWo1 = (ushort_t*)(wsb + 417792);   // 221184
    ushort_t* BWo2 = (ushort_t*)(wsb + 860160);   //  16384
    // activation regions (bytes): P1/P2/P3 8MB each, P4 16MB; total 41MB
    ushort_t* P1 = (ushort_t*)(wsb + 1048576);
    ushort_t* P2 = (ushort_t*)(wsb + 9437184);
    ushort_t* P3 = (ushort_t*)(wsb + 17825792);
    ushort_t* P4 = (ushort_t*)(wsb + 26214400);

    ushort_t* xh_c = P1;   // (16384 px, 256)
    ushort_t* c1   = P2;   // (16384 px, 64)
    ushort_t* x1   = P3;   // (65536 px, 64)
    ushort_t* xl_c = P4;   // (65536 px, 128)
    ushort_t* x2   = P2;   // (65536 px, 64)
    ushort_t* wm   = P1;   // (65536 px, 32)  logits->softmax in place
    ushort_t* xh2  = P3;   // (16384 px, 256) second conversion
    ushort_t* xr   = P2;   // (16384 px, 64)
    ushort_t* xu   = P3;   // (65536 px, 64)
    ushort_t* Xb   = P2;   // (65536 px, 64)
    ushort_t* y1a  = P1;   // (32768 px, 128)
    ushort_t* y1b  = P3;   // (32768 px, 128)

    // 0) weights -> bf16 [tap][co][ci]
    prep_weights<<<1744, 256, 0, stream>>>(w_reduce, w1, w2, w_enc, w_out1, w_out2,
                                           BWr, BW1, BW2, BWe, BWo1, BWo2);
    // 1) x_h -> NHWC bf16
    nchw2nhwc<<<64, 256, 0, stream>>>(x_h, xh_c, 256, 12, 16384);
    // 2) c1 = cbr1x1(xh_c, w1): M=16384 K=256 CO=64
    conv_mfma<1, 1, 4, 0><<<dim3(256, 1), 256, 0, stream>>>(
        xh_c, 256, 256, nullptr, 0, nullptr, 0, 0,
        BW1, 64, 256, g1, b1, 64,
        c1, nullptr, 0, 64, 6, 64, 16384, 12, 1);
    // 3) x1 = resize2x(c1)
    resize2x_nhwc<<<2048, 256, 0, stream>>>(c1, x1, 64, 64, 128, 128, 64);
    // 4) x_l -> NHWC bf16
    nchw2nhwc<<<256, 256, 0, stream>>>(x_l, xl_c, 128, 14, 65536);
    // 5) x2 = cbr1x1(xl_c, w2): M=65536 K=128 CO=64
    conv_mfma<1, 2, 4, 0><<<dim3(512, 1), 256, 0, stream>>>(
        xl_c, 128, 128, nullptr, 0, nullptr, 0, 0,
        BW2, 64, 128, g2, b2, 64,
        x2, nullptr, 0, 64, 7, 128, 65536, 14, 1);
    // 6) wm = conv3x3(concat(x1,x2), w_enc), no relu: CO=32(25 real)
    conv_mfma<9, 4, 2, 0><<<dim3(256, 1), 256, 0, stream>>>(
        x1, 64, 64, nullptr, 0, x2, 64, 64,
        BWe, 32, 128, g_enc, b_enc, 25,
        wm, nullptr, 0, 32, 7, 128, 65536, 14, 0);
    // 7) softmax over 25 channels (in place)
    softmax25<<<256, 256, 0, stream>>>(wm, 65536);
    // 8) x_h -> NHWC bf16 (again; P1 was reused for wm)
    nchw2nhwc<<<64, 256, 0, stream>>>(x_h, xh2, 256, 12, 16384);
    // 9) xr = cbr3x3(xh2, w_reduce): M=16384 K=256*9 CO=64 @64x64
    conv_mfma<9, 1, 4, 0><<<dim3(256, 1), 256, 0, stream>>>(
        xh2, 256, 256, nullptr, 0, nullptr, 0, 0,
        BWr, 64, 256, g_reduce, b_reduce, 64,
        xr, nullptr, 0, 64, 6, 64, 16384, 12, 1);
    // 10) xu = resize2x(xr)
    resize2x_nhwc<<<2048, 256, 0, stream>>>(xr, xu, 64, 64, 128, 128, 64);
    // 11) X = carafe(wm, xu)
    carafe25<<<2048, 256, 0, stream>>>(wm, xu, Xb);
    // 12) y1 = cbr3x3(concat(X, xl_c), w_out1): CO=128, output split in px halves
    conv_mfma<9, 4, 4, 0><<<dim3(256, 2), 256, 0, stream>>>(
        Xb, 64, 64, nullptr, 0, xl_c, 128, 128,
        BWo1, 128, 192, g_out1, b_out1, 128,
        y1a, y1b, 32768, 128, 7, 128, 65536, 14, 1);
    // 13) out = cbr1x1(y1, w_out2) -> d_out NCHW f32
    conv_mfma<1, 4, 4, 1><<<dim3(256, 2), 256, 0, stream>>>(
        y1a, 128, 128, y1b, 32768, nullptr, 0, 0,
        BWo2, 128, 128, g_out2, b_out2, 128,
        d_out, nullptr, 0, 0, 7, 128, 65536, 14, 1);
}

// Round 3
// 293.906 us; speedup vs baseline: 5.6415x; 1.0774x over previous
//
#include <hip/hip_runtime.h>
#include <math.h>

#define BNS 0.99999500003749981f  // 1/sqrt(1+1e-5)

typedef short          bf16x8  __attribute__((ext_vector_type(8)));
typedef float          f32x4   __attribute__((ext_vector_type(4)));
typedef unsigned short u16x8   __attribute__((ext_vector_type(8)));
typedef unsigned short u16x4   __attribute__((ext_vector_type(4)));
typedef unsigned short ushort_t;

__device__ inline ushort_t f2b(float f) {
    union { float f; unsigned int u; } x; x.f = f;
    unsigned int u = x.u;
    unsigned int r = (u + 0x7FFFu + ((u >> 16) & 1u)) >> 16;   // RNE
    return (ushort_t)r;
}
__device__ inline float b2f(ushort_t s) {
    union { unsigned int u; float f; } x; x.u = ((unsigned int)s) << 16;
    return x.f;
}

// ---------------- workspace element offsets (ushort units) ----------------
#define E_BWR   0u
#define E_BW1   147456u
#define E_BW2   163840u
#define E_BWE   172032u
#define E_BWO1  208896u
#define E_BWO2  430080u
#define E_ZP    446464u      // 64KB zero page (32768 el)
#define OFF_R1  524288u      // 8MB  region  (byte 1048576)
#define OFF_R4  4718592u     // 8MB           (byte 9437184)
#define OFF_R2  8912896u     // 2MB           (byte 17825792)
#define OFF_R3  9961472u     // 2MB           (byte 19922944)
#define OFF_R6  11010048u    // 4MB           (byte 22020096)
#define OFF_R5  13107200u    // 16MB          (byte 26214400) end byte 42991616

// ============================================================================
// Weight prep: OIHW f32 -> [tap][co][ciT] bf16, plus 64KB zero page.
// ============================================================================
__device__ inline void wseg(int lidx, const float* src, ushort_t* dst,
                            int TAPS, int CO, int CIT, int CO_real) {
    int tap = lidx / (CO * CIT);
    int r   = lidx - tap * (CO * CIT);
    int co  = r / CIT;
    int ci  = r - co * CIT;
    float v = (co < CO_real) ? src[(size_t)(co * CIT + ci) * TAPS + tap] : 0.f;
    dst[((size_t)tap * CO + co) * CIT + ci] = f2b(v);
}

__global__ __launch_bounds__(256)
void prep_weights(const float* wr, const float* w1, const float* w2,
                  const float* we, const float* wo1, const float* wo2,
                  ushort_t* ws0)
{
    int idx = blockIdx.x * 256 + threadIdx.x;
    const int n0 = 9*64*256;    // reduce   147456
    const int n1 = 64*256;      // w1        16384
    const int n2 = 64*128;      // w2         8192
    const int n3 = 9*32*128;    // enc       36864
    const int n4 = 9*128*192;   // out1     221184
    const int n5 = 128*128;     // out2      16384
    if (idx < n0) { wseg(idx, wr, ws0 + E_BWR, 9, 64, 256, 64); return; } idx -= n0;
    if (idx < n1) { wseg(idx, w1, ws0 + E_BW1, 1, 64, 256, 64); return; } idx -= n1;
    if (idx < n2) { wseg(idx, w2, ws0 + E_BW2, 1, 64, 128, 64); return; } idx -= n2;
    if (idx < n3) { wseg(idx, we, ws0 + E_BWE, 9, 32, 128, 25); return; } idx -= n3;
    if (idx < n4) { wseg(idx, wo1, ws0 + E_BWO1, 9, 128, 192, 128); return; } idx -= n4;
    if (idx < n5) { wseg(idx, wo2, ws0 + E_BWO2, 1, 128, 128, 128); return; } idx -= n5;
    if (idx < 32768) ws0[E_ZP + idx] = 0;   // zero page
}

// ============================================================================
// NCHW f32 -> NHWC bf16
// ============================================================================
__global__ __launch_bounds__(256)
void nchw2nhwc(const float* __restrict__ in, ushort_t* __restrict__ out,
               int C, int LHW, int npx)
{
    int px = blockIdx.x * 256 + threadIdx.x;
    if (px >= npx) return;
    int HW = 1 << LHW;
    int b = px >> LHW, phw = px & (HW - 1);
    const float* src = in + (size_t)b * C * HW + phw;
    ushort_t* dst = out + (size_t)px * C;
    for (int c0 = 0; c0 < C; c0 += 8) {
        u16x8 o;
#pragma unroll
        for (int j = 0; j < 8; j++) o[j] = f2b(src[(size_t)(c0 + j) * HW]);
        *reinterpret_cast<u16x8*>(dst + c0) = o;
    }
}

// ============================================================================
// Implicit-GEMM conv, bf16 MFMA 16x16x32, fully-unrolled flattened K loop
// with explicit depth-2 register software pipeline (3 rotating slots).
// A-operand = weights [tap][co][ciT]; B-operand = NHWC activations (concat of
// up to 2 sources). Border taps read a zeroed ws page (offset select only).
// ============================================================================
template<int TAPS, int MF, int NF, int CIA, int CIB, int COT, int EPI>
__global__ __launch_bounds__(256, 2)
void conv_mfma(const ushort_t* __restrict__ ws0,
               unsigned offA, unsigned offB, unsigned offW,
               const float* __restrict__ g, const float* __restrict__ bia,
               int COclamp, void* __restrict__ outp, int ldo,
               int LW, int H, int LHW, int relu)
{
    constexpr int CIT = CIA + CIB;
    constexpr int KCA = CIA / 32;
    constexpr int KCB = CIB / 32;
    constexpr int KCT = KCA + KCB;
    constexpr int KT  = TAPS * KCT;
    constexpr int NTAP = (TAPS == 9) ? 9 : 1;
    constexpr int LA = (CIA == 256) ? 8 : (CIA == 128) ? 7 : (CIA == 64) ? 6 : 0;
    constexpr int LB = (CIB == 256) ? 8 : (CIB == 128) ? 7 : (CIB == 64) ? 6 : 0;

    const int lane = threadIdx.x & 63;
    const int wid  = threadIdx.x >> 6;
    const int l15  = lane & 15, lhi = lane >> 4;
    const int khi8 = lhi * 8;
    const int px0  = blockIdx.x * (64 * MF) + wid * (MF * 16);
    const int co_base = blockIdx.y * (NF * 16);
    const int W = 1 << LW;

    int m_[MF];
#pragma unroll
    for (int mf = 0; mf < MF; ++mf) m_[mf] = px0 + mf * 16 + l15;

    // per-tap uniform pixel deltas (SGPR) + per-(tap,mf) validity bits
    int sD[NTAP];
    unsigned long long okb = ~0ull;
    if (TAPS == 9) {
        okb = 0ull;
        int ym[MF], xm[MF];
#pragma unroll
        for (int mf = 0; mf < MF; ++mf) {
            ym[mf] = (m_[mf] >> LW) & (H - 1);
            xm[mf] = m_[mf] & (W - 1);
        }
#pragma unroll
        for (int tap = 0; tap < 9; ++tap) {
            const int dy = tap / 3 - 1, dx = tap % 3 - 1;
            sD[tap] = dy * W + dx;
#pragma unroll
            for (int mf = 0; mf < MF; ++mf) {
                int yy = ym[mf] + dy, xx = xm[mf] + dx;
                bool ok = (yy >= 0) & (yy < H) & (xx >= 0) & (xx < W);
                okb |= ((unsigned long long)ok) << (tap * MF + mf);
            }
        }
    } else {
        sD[0] = 0;
    }

    unsigned wrow[NF];
#pragma unroll
    for (int nf = 0; nf < NF; ++nf)
        wrow[nf] = offW + (unsigned)(co_base + nf * 16 + l15) * CIT + khi8;

    f32x4 acc[NF][MF];
#pragma unroll
    for (int nf = 0; nf < NF; ++nf)
#pragma unroll
        for (int mf = 0; mf < MF; ++mf)
            acc[nf][mf] = (f32x4){0.f, 0.f, 0.f, 0.f};

    bf16x8 bq[3][MF], wq[3][NF];
    unsigned rowCur[MF];

#pragma unroll
    for (int kt = 0; kt < KT + 2; ++kt) {
        if (kt < KT) {                       // ---- issue loads for ktile kt
            const int tap = kt / KCT;
            const int j   = kt - tap * KCT;
            const bool isA = (j < KCA);
            const int kc  = isA ? j : (j - KCA);
            const int sl  = kt % 3;
            if (kc == 0) {                   // new (tap, source) segment
#pragma unroll
                for (int mf = 0; mf < MF; ++mf) {
                    unsigned r;
                    if (isA) r = offA + ((unsigned)(m_[mf] + sD[TAPS == 9 ? tap : 0]) << LA);
                    else     r = offB + ((unsigned)(m_[mf] + sD[TAPS == 9 ? tap : 0]) << LB);
                    r += (unsigned)khi8;
                    if (TAPS == 9) {
                        bool ok = (okb >> (tap * MF + mf)) & 1ull;
                        r = ok ? r : E_ZP;
                    }
                    rowCur[mf] = r;
                }
            }
#pragma unroll
            for (int mf = 0; mf < MF; ++mf)
                bq[sl][mf] = *reinterpret_cast<const bf16x8*>(ws0 + rowCur[mf] + kc * 32);
            const unsigned wc = (unsigned)(tap * (COT * CIT) + (isA ? 0 : CIA) + kc * 32);
#pragma unroll
            for (int nf = 0; nf < NF; ++nf)
                wq[sl][nf] = *reinterpret_cast<const bf16x8*>(ws0 + wrow[nf] + wc);
        }
        if (kt >= 2) {                       // ---- MFMA ktile kt-2
            const int sl = (kt - 2) % 3;
#pragma unroll
            for (int nf = 0; nf < NF; ++nf)
#pragma unroll
                for (int mf = 0; mf < MF; ++mf)
                    acc[nf][mf] = __builtin_amdgcn_mfma_f32_16x16x32_bf16(
                        wq[sl][nf], bq[sl][mf], acc[nf][mf], 0, 0, 0);
        }
    }

    // ---------------- epilogue ----------------
    const int cob = co_base + (lhi << 2);
    if (EPI == 0) {
        ushort_t* o1 = (ushort_t*)outp;
#pragma unroll
        for (int nf = 0; nf < NF; ++nf) {
            float sc[4], bi[4];
#pragma unroll
            for (int r = 0; r < 4; r++) {
                int c = min(cob + nf * 16 + r, COclamp - 1);
                sc[r] = g[c] * BNS; bi[r] = bia[c];
            }
#pragma unroll
            for (int mf = 0; mf < MF; ++mf) {
                f32x4 a = acc[nf][mf];
                u16x4 ov;
#pragma unroll
                for (int r = 0; r < 4; r++) {
                    float v = fmaf(a[r], sc[r], bi[r]);
                    if (relu) v = fmaxf(v, 0.f);
                    ov[r] = f2b(v);
                }
                int px = px0 + mf * 16 + l15;
                *reinterpret_cast<u16x4*>(
                    o1 + (size_t)px * ldo + co_base + nf * 16 + (lhi << 2)) = ov;
            }
        }
    } else {
        float* o1 = (float*)outp;
        const int HW = 1 << LHW;
#pragma unroll
        for (int nf = 0; nf < NF; ++nf) {
            float sc[4], bi[4];
#pragma unroll
            for (int r = 0; r < 4; r++) {
                int c = min(cob + nf * 16 + r, COclamp - 1);
                sc[r] = g[c] * BNS; bi[r] = bia[c];
            }
#pragma unroll
            for (int mf = 0; mf < MF; ++mf) {
                int px = px0 + mf * 16 + l15;
                int b = px >> LHW, phw = px & (HW - 1);
#pragma unroll
                for (int r = 0; r < 4; r++) {
                    float v = fmaf(acc[nf][mf][r], sc[r], bi[r]);
                    if (relu) v = fmaxf(v, 0.f);
                    o1[((size_t)(b * COT + cob + nf * 16 + r)) * HW + phw] = v;
                }
            }
        }
    }
}

// ============================================================================
// 2x bilinear resize (align-corners linspace), NHWC bf16, C=64
// ============================================================================
__global__ __launch_bounds__(256)
void resize2x_nhwc(const ushort_t* __restrict__ in, ushort_t* __restrict__ out,
                   int Hi, int Wi, int Ho, int Wo, int C)
{
    int t = blockIdx.x * 256 + threadIdx.x;
    int cg = t & 7;
    int opx = t >> 3;
    int xo = opx & (Wo - 1);
    int rest = opx >> 7;
    int yo = rest & (Ho - 1);
    int b  = rest >> 7;
    float fy = (float)yo * (float)(Hi - 1) / (float)(Ho - 1);
    float fx = (float)xo * (float)(Wi - 1) / (float)(Wo - 1);
    int y0 = (int)fy, x0 = (int)fx;
    float wy = fy - (float)y0, wx = fx - (float)x0;
    int y1 = min(y0 + 1, Hi - 1), x1 = min(x0 + 1, Wi - 1);
    size_t base = ((size_t)b * Hi) * Wi;
    bf16x8 v00 = *reinterpret_cast<const bf16x8*>(in + (base + (size_t)y0 * Wi + x0) * C + cg * 8);
    bf16x8 v01 = *reinterpret_cast<const bf16x8*>(in + (base + (size_t)y0 * Wi + x1) * C + cg * 8);
    bf16x8 v10 = *reinterpret_cast<const bf16x8*>(in + (base + (size_t)y1 * Wi + x0) * C + cg * 8);
    bf16x8 v11 = *reinterpret_cast<const bf16x8*>(in + (base + (size_t)y1 * Wi + x1) * C + cg * 8);
    u16x8 o;
#pragma unroll
    for (int k = 0; k < 8; k++) {
        float l = b2f((ushort_t)v00[k]) * (1.f - wy) + b2f((ushort_t)v10[k]) * wy;
        float r = b2f((ushort_t)v01[k]) * (1.f - wy) + b2f((ushort_t)v11[k]) * wy;
        o[k] = f2b(l * (1.f - wx) + r * wx);
    }
    *reinterpret_cast<u16x8*>(out + (size_t)opx * C + cg * 8) = o;
}

// ============================================================================
// softmax over 25 channels, NHWC stride 32 bf16, in place
// ============================================================================
__global__ __launch_bounds__(256)
void softmax25(ushort_t* __restrict__ wm, int npx)
{
    int px = blockIdx.x * 256 + threadIdx.x;
    if (px >= npx) return;
    ushort_t* p = wm + (size_t)px * 32;
    u16x8 r0 = *reinterpret_cast<u16x8*>(p);
    u16x8 r1 = *reinterpret_cast<u16x8*>(p + 8);
    u16x8 r2 = *reinterpret_cast<u16x8*>(p + 16);
    u16x8 r3 = *reinterpret_cast<u16x8*>(p + 24);
    float v[25];
#pragma unroll
    for (int k = 0; k < 8; k++) v[k]      = b2f(r0[k]);
#pragma unroll
    for (int k = 0; k < 8; k++) v[8 + k]  = b2f(r1[k]);
#pragma unroll
    for (int k = 0; k < 8; k++) v[16 + k] = b2f(r2[k]);
    v[24] = b2f(r3[0]);
    float m = v[0];
#pragma unroll
    for (int c = 1; c < 25; c++) m = fmaxf(m, v[c]);
    float s = 0.f;
#pragma unroll
    for (int c = 0; c < 25; c++) { v[c] = __expf(v[c] - m); s += v[c]; }
    float inv = 1.f / s;
#pragma unroll
    for (int c = 0; c < 25; c++) p[c] = f2b(v[c] * inv);
}

// ============================================================================
// CARAFE combine (NHWC bf16, C=64, H=W=128)
// ============================================================================
__global__ __launch_bounds__(256)
void carafe25(const ushort_t* __restrict__ wm, const ushort_t* __restrict__ xu,
              ushort_t* __restrict__ out)
{
    int t = blockIdx.x * 256 + threadIdx.x;
    int cg = t & 7;
    int px = t >> 3;
    int x = px & 127;
    int y = (px >> 7) & 127;
    const ushort_t* wp = wm + (size_t)px * 32;
    float acc[8];
#pragma unroll
    for (int k = 0; k < 8; k++) acc[k] = 0.f;
#pragma unroll 1
    for (int i = 0; i < 5; i++) {
        int yy = y + 2 * i - 4;
        if (yy < 0 || yy > 127) continue;
#pragma unroll
        for (int j = 0; j < 5; j++) {
            int xx = x + 2 * j - 4;
            if (xx < 0 || xx > 127) continue;
            float wv = b2f(wp[i * 5 + j]);
            int q = px + (2 * i - 4) * 128 + (2 * j - 4);
            bf16x8 xv = *reinterpret_cast<const bf16x8*>(xu + (size_t)q * 64 + cg * 8);
#pragma unroll
            for (int k = 0; k < 8; k++)
                acc[k] = fmaf(wv, b2f((ushort_t)xv[k]), acc[k]);
        }
    }
    u16x8 o;
#pragma unroll
    for (int k = 0; k < 8; k++) o[k] = f2b(acc[k]);
    *reinterpret_cast<u16x8*>(out + (size_t)px * 64 + cg * 8) = o;
}

// ============================================================================
extern "C" void kernel_launch(void* const* d_in, const int* in_sizes, int n_in,
                              void* d_out, int out_size, void* d_ws, size_t ws_size,
                              hipStream_t stream)
{
    const float* x_h      = (const float*)d_in[0];
    const float* x_l      = (const float*)d_in[1];
    const float* w_reduce = (const float*)d_in[2];
    const float* g_reduce = (const float*)d_in[3];
    const float* b_reduce = (const float*)d_in[4];
    const float* w1       = (const float*)d_in[5];
    const float* g1       = (const float*)d_in[6];
    const float* b1       = (const float*)d_in[7];
    const float* w2       = (const float*)d_in[8];
    const float* g2       = (const float*)d_in[9];
    const float* b2       = (const float*)d_in[10];
    const float* w_enc    = (const float*)d_in[11];
    const float* g_enc    = (const float*)d_in[12];
    const float* b_enc    = (const float*)d_in[13];
    const float* w_out1   = (const float*)d_in[14];
    const float* g_out1   = (const float*)d_in[15];
    const float* b_out1   = (const float*)d_in[16];
    const float* w_out2   = (const float*)d_in[17];
    const float* g_out2   = (const float*)d_in[18];
    const float* b_out2   = (const float*)d_in[19];

    ushort_t* ws0 = (ushort_t*)d_ws;

    // buffer aliases (element offsets)
    const unsigned oXHC = OFF_R1;   // (16384, 256)
    const unsigned oC1  = OFF_R2;   // (16384, 64)
    const unsigned oXR  = OFF_R3;   // (16384, 64)
    const unsigned oX1  = OFF_R4;   // (65536, 64)
    const unsigned oXLC = OFF_R5;   // (65536, 128)
    const unsigned oX2  = OFF_R1;   // (65536, 64)   xh_c dead
    const unsigned oWM  = OFF_R6;   // (65536, 32)
    const unsigned oXU  = OFF_R4;   // (65536, 64)   x1 dead
    const unsigned oXB  = OFF_R1;   // (65536, 64)   x2 dead
    const unsigned oY1  = OFF_R4;   // (65536, 128)  contiguous R4+R2+R3+R6

    // 0) weights -> bf16 [tap][co][ci] + zero page
    prep_weights<<<1872, 256, 0, stream>>>(w_reduce, w1, w2, w_enc, w_out1, w_out2, ws0);
    // 1) x_h -> NHWC bf16
    nchw2nhwc<<<64, 256, 0, stream>>>(x_h, ws0 + oXHC, 256, 12, 16384);
    // 2) c1 = cbr1x1(xh_c, w1): M=16384 K=256 CO=64
    conv_mfma<1, 1, 4, 256, 0, 64, 0><<<dim3(256, 1), 256, 0, stream>>>(
        ws0, oXHC, 0u, E_BW1, g1, b1, 64, ws0 + oC1, 64, 6, 64, 12, 1);
    // 3) xr = cbr3x3(xh_c, w_reduce): M=16384 K=256*9 CO=64
    conv_mfma<9, 1, 2, 256, 0, 64, 0><<<dim3(256, 2), 256, 0, stream>>>(
        ws0, oXHC, 0u, E_BWR, g_reduce, b_reduce, 64, ws0 + oXR, 64, 6, 64, 12, 1);
    // 4) x1 = resize2x(c1)
    resize2x_nhwc<<<2048, 256, 0, stream>>>(ws0 + oC1, ws0 + oX1, 64, 64, 128, 128, 64);
    // 5) x_l -> NHWC bf16
    nchw2nhwc<<<256, 256, 0, stream>>>(x_l, ws0 + oXLC, 128, 14, 65536);
    // 6) x2 = cbr1x1(xl_c, w2): M=65536 K=128 CO=64
    conv_mfma<1, 2, 4, 128, 0, 64, 0><<<dim3(512, 1), 256, 0, stream>>>(
        ws0, oXLC, 0u, E_BW2, g2, b2, 64, ws0 + oX2, 64, 7, 128, 14, 1);
    // 7) wm = conv3x3(concat(x1,x2), w_enc), no relu: CO=32(25 real)
    conv_mfma<9, 2, 2, 64, 64, 32, 0><<<dim3(512, 1), 256, 0, stream>>>(
        ws0, oX1, oX2, E_BWE, g_enc, b_enc, 25, ws0 + oWM, 32, 7, 128, 14, 0);
    // 8) softmax over 25 mask channels (in place)
    softmax25<<<256, 256, 0, stream>>>(ws0 + oWM, 65536);
    // 9) xu = resize2x(xr)
    resize2x_nhwc<<<2048, 256, 0, stream>>>(ws0 + oXR, ws0 + oXU, 64, 64, 128, 128, 64);
    // 10) X = carafe(wm, xu)
    carafe25<<<2048, 256, 0, stream>>>(ws0 + oWM, ws0 + oXU, ws0 + oXB);
    // 11) y1 = cbr3x3(concat(X, xl_c), w_out1): CO=128
    conv_mfma<9, 4, 4, 64, 128, 128, 0><<<dim3(256, 2), 256, 0, stream>>>(
        ws0, oXB, oXLC, E_BWO1, g_out1, b_out1, 128, ws0 + oY1, 128, 7, 128, 14, 1);
    // 12) out = cbr1x1(y1, w_out2) -> d_out NCHW f32
    conv_mfma<1, 4, 4, 128, 0, 128, 1><<<dim3(256, 2), 256, 0, stream>>>(
        ws0, oY1, 0u, E_BWO2, g_out2, b_out2, 128, d_out, 0, 7, 128, 14, 1);
}

// Round 4
// 214.176 us; speedup vs baseline: 7.7417x; 1.3723x over previous
//
#include <hip/hip_runtime.h>
#include <math.h>

#define BNS 0.99999500003749981f  // 1/sqrt(1+1e-5)

typedef short          bf16x8  __attribute__((ext_vector_type(8)));
typedef float          f32x4   __attribute__((ext_vector_type(4)));
typedef unsigned short u16x8   __attribute__((ext_vector_type(8)));
typedef unsigned short u16x4   __attribute__((ext_vector_type(4)));
typedef unsigned short ushort_t;

__device__ inline ushort_t f2b(float f) {
    union { float f; unsigned int u; } x; x.f = f;
    unsigned int u = x.u;
    unsigned int r = (u + 0x7FFFu + ((u >> 16) & 1u)) >> 16;   // RNE
    return (ushort_t)r;
}
__device__ inline float b2f(ushort_t s) {
    union { unsigned int u; float f; } x; x.u = ((unsigned int)s) << 16;
    return x.f;
}

// ---------------- workspace element offsets (ushort units) ----------------
#define E_BWR   0u
#define E_BW1   147456u
#define E_BW2   163840u
#define E_BWE   172032u
#define E_BWO1  208896u
#define E_BWO2  430080u
#define E_ZP    446464u      // 64KB zero page (32768 el)
#define OFF_R1  524288u      // 8MB region   (byte 1048576)
#define OFF_R4  4718592u     // 8MB          (byte 9437184)
#define OFF_R2  8912896u     // 2MB          (byte 17825792)
#define OFF_R3  9961472u     // 2MB          (byte 19922944)
#define OFF_R6  11010048u    // 4MB          (byte 22020096)
#define OFF_R5  13107200u    // 16MB         (byte 26214400) end byte 42991616

// T16 activation layout: element (px, ci) of a CI-channel tensor lives at
//   (px>>4)*(CI*16) + (ci>>3)*128 + (px&15)*8 + (ci&7)
// -> any (16px x 8ci) fragment slice is 16B/lane within a 256B chunk.

// ============================================================================
// Weight prep: OIHW f32 -> [ktile][co][32ci] bf16 (ktile = tap*KCT + j, where
// j enumerates A-source 32ci-chunks then B-source chunks). Fragment load for
// 16 co x 16B is 1KB contiguous. Plus 64KB zero page.
// ============================================================================
__device__ inline void wseg2(int idx, const float* src, ushort_t* dst,
                             int TAPS, int COT, int CIT, int CO_real) {
    int kt  = idx / (COT * 32);
    int rem = idx - kt * (COT * 32);
    int co  = rem >> 5;
    int c   = rem & 31;
    int KCT = CIT >> 5;
    int tap = kt / KCT, j = kt - tap * KCT;
    int ci_w = j * 32 + c;
    float v = (co < CO_real) ? src[((size_t)co * CIT + ci_w) * TAPS + tap] : 0.f;
    dst[idx] = f2b(v);
}

__global__ __launch_bounds__(256)
void prep_weights(const float* wr, const float* w1, const float* w2,
                  const float* we, const float* wo1, const float* wo2,
                  ushort_t* ws0)
{
    int idx = blockIdx.x * 256 + threadIdx.x;
    const int n0 = 9*64*256;    // reduce   147456
    const int n1 = 64*256;      // w1        16384
    const int n2 = 64*128;      // w2         8192
    const int n3 = 9*32*128;    // enc       36864
    const int n4 = 9*128*192;   // out1     221184
    const int n5 = 128*128;     // out2      16384
    if (idx < n0) { wseg2(idx, wr,  ws0 + E_BWR,  9, 64, 256, 64);  return; } idx -= n0;
    if (idx < n1) { wseg2(idx, w1,  ws0 + E_BW1,  1, 64, 256, 64);  return; } idx -= n1;
    if (idx < n2) { wseg2(idx, w2,  ws0 + E_BW2,  1, 64, 128, 64);  return; } idx -= n2;
    if (idx < n3) { wseg2(idx, we,  ws0 + E_BWE,  9, 32, 128, 25);  return; } idx -= n3;
    if (idx < n4) { wseg2(idx, wo1, ws0 + E_BWO1, 9, 128, 192, 128); return; } idx -= n4;
    if (idx < n5) { wseg2(idx, wo2, ws0 + E_BWO2, 1, 128, 128, 128); return; } idx -= n5;
    if (idx < 32768) ws0[E_ZP + idx] = 0;   // zero page
}

// ============================================================================
// NCHW f32 -> T16 bf16
// ============================================================================
__global__ __launch_bounds__(256)
void nchw2t16(const float* __restrict__ in, ushort_t* __restrict__ out,
              int C, int LHW, int npx)
{
    int px = blockIdx.x * 256 + threadIdx.x;
    if (px >= npx) return;
    int HW = 1 << LHW;
    int b = px >> LHW, phw = px & (HW - 1);
    const float* src = in + (size_t)b * C * HW + phw;
    unsigned base = (unsigned)(px >> 4) * (C * 16) + (unsigned)(px & 15) * 8;
    for (int c0 = 0; c0 < C; c0 += 8) {
        u16x8 o;
#pragma unroll
        for (int j = 0; j < 8; j++) o[j] = f2b(src[(size_t)(c0 + j) * HW]);
        *reinterpret_cast<u16x8*>(out + base + (c0 >> 3) * 128) = o;
    }
}

// ============================================================================
// Implicit-GEMM conv, bf16 MFMA 16x16x32, flattened fully-unrolled K loop,
// 3-slot register pipeline, T16 act layout + [kt][co][32] weight layout
// (both operand loads coalesced). Bijective XCD-chunked block swizzle.
// ============================================================================
template<int TAPS, int MF, int NF, int CIA, int CIB, int COT, int GYL, int EPI>
__global__ __launch_bounds__(256, 2)
void conv_mfma(const ushort_t* __restrict__ ws0,
               unsigned offA, unsigned offB, unsigned offW,
               const float* __restrict__ g, const float* __restrict__ bia,
               int COclamp, void* __restrict__ outp,
               int LW, int H, int LHW, int relu)
{
    constexpr int CIT = CIA + CIB;
    constexpr int KCA = CIA / 32;
    constexpr int KCT = CIT / 32;
    constexpr int KT  = TAPS * KCT;
    constexpr int NTAP = (TAPS == 9) ? 9 : 1;

    // ---- bijective XCD-chunked swizzle (m204), y fastest in logical order
    const unsigned GY   = 1u << GYL;
    const unsigned nwg  = gridDim.x << GYL;
    const unsigned orig = blockIdx.y * gridDim.x + blockIdx.x;
    const unsigned qq   = nwg >> 3, r8 = nwg & 7;
    const unsigned xcd  = orig & 7, kk0 = orig >> 3;
    const unsigned logical = (xcd < r8 ? xcd * (qq + 1)
                                       : r8 * (qq + 1) + (xcd - r8) * qq) + kk0;
    const unsigned by = logical & (GY - 1);
    const unsigned bx = logical >> GYL;

    const int lane = threadIdx.x & 63;
    const int wid  = threadIdx.x >> 6;
    const int l15  = lane & 15, lhi = lane >> 4;
    const int px0  = (int)bx * (64 * MF) + wid * (MF * 16);
    const int co_base = (int)by * (NF * 16);
    const int W = 1 << LW;

    int m_[MF];
#pragma unroll
    for (int mf = 0; mf < MF; ++mf) m_[mf] = px0 + mf * 16 + l15;

    int sD[NTAP];
    unsigned long long okb = ~0ull;
    if (TAPS == 9) {
        okb = 0ull;
        int ym[MF], xm[MF];
#pragma unroll
        for (int mf = 0; mf < MF; ++mf) {
            ym[mf] = (m_[mf] >> LW) & (H - 1);
            xm[mf] = m_[mf] & (W - 1);
        }
#pragma unroll
        for (int tap = 0; tap < 9; ++tap) {
            const int dy = tap / 3 - 1, dx = tap % 3 - 1;
            sD[tap] = dy * W + dx;
#pragma unroll
            for (int mf = 0; mf < MF; ++mf) {
                int yy = ym[mf] + dy, xx = xm[mf] + dx;
                bool ok = (yy >= 0) & (yy < H) & (xx >= 0) & (xx < W);
                okb |= ((unsigned long long)ok) << (tap * MF + mf);
            }
        }
    } else {
        sD[0] = 0;
    }

    // weight rows: [kt][co][32] -> lane off = co*32 + lhi*8
    unsigned wrow[NF];
#pragma unroll
    for (int nf = 0; nf < NF; ++nf)
        wrow[nf] = offW + (unsigned)(co_base + nf * 16 + l15) * 32 + (unsigned)(lhi << 3);

    f32x4 acc[NF][MF];
#pragma unroll
    for (int nf = 0; nf < NF; ++nf)
#pragma unroll
        for (int mf = 0; mf < MF; ++mf)
            acc[nf][mf] = (f32x4){0.f, 0.f, 0.f, 0.f};

    bf16x8 bq[3][MF], wq[3][NF];
    unsigned rowCur[MF];

#pragma unroll
    for (int kt = 0; kt < KT + 2; ++kt) {
        if (kt < KT) {
            const int tap = kt / KCT;
            const int j   = kt - tap * KCT;
            const bool isA = (j < KCA);
            const int kc  = isA ? j : (j - KCA);
            const int sl  = kt % 3;
            if (kc == 0) {                   // new (tap, source) segment
#pragma unroll
                for (int mf = 0; mf < MF; ++mf) {
                    int px = m_[mf] + ((TAPS == 9) ? sD[tap] : 0);
                    unsigned r;
                    if (isA) r = offA + (unsigned)((px >> 4) * (CIA * 16));
                    else     r = offB + (unsigned)((px >> 4) * (CIB * 16));
                    r += ((unsigned)(px & 15) << 3) + ((unsigned)lhi << 7);
                    if (TAPS == 9) {
                        bool ok = (okb >> (tap * MF + mf)) & 1ull;
                        r = ok ? r : E_ZP;
                    }
                    rowCur[mf] = r;
                }
            }
#pragma unroll
            for (int mf = 0; mf < MF; ++mf)
                bq[sl][mf] = *reinterpret_cast<const bf16x8*>(ws0 + rowCur[mf] + kc * 512);
            const unsigned wc = (unsigned)kt * (COT * 32);
#pragma unroll
            for (int nf = 0; nf < NF; ++nf)
                wq[sl][nf] = *reinterpret_cast<const bf16x8*>(ws0 + wrow[nf] + wc);
        }
        if (kt >= 2) {
            const int sl = (kt - 2) % 3;
#pragma unroll
            for (int nf = 0; nf < NF; ++nf)
#pragma unroll
                for (int mf = 0; mf < MF; ++mf)
                    acc[nf][mf] = __builtin_amdgcn_mfma_f32_16x16x32_bf16(
                        wq[sl][nf], bq[sl][mf], acc[nf][mf], 0, 0, 0);
        }
    }

    // ---------------- epilogue ----------------
    if (EPI == 0) {
        ushort_t* o1 = (ushort_t*)outp;
#pragma unroll
        for (int nf = 0; nf < NF; ++nf) {
            const int cq = co_base + nf * 16 + (lhi << 2);   // first of 4 co
            float sc[4], bi[4];
#pragma unroll
            for (int r = 0; r < 4; r++) {
                int c = min(cq + r, COclamp - 1);
                sc[r] = g[c] * BNS; bi[r] = bia[c];
            }
#pragma unroll
            for (int mf = 0; mf < MF; ++mf) {
                f32x4 a = acc[nf][mf];
                u16x4 ov;
#pragma unroll
                for (int r = 0; r < 4; r++) {
                    float v = fmaf(a[r], sc[r], bi[r]);
                    if (relu) v = fmaxf(v, 0.f);
                    ov[r] = f2b(v);
                }
                int px = px0 + mf * 16 + l15;
                unsigned off = (unsigned)(px >> 4) * (COT * 16)
                             + (unsigned)(cq >> 3) * 128
                             + (unsigned)(px & 15) * 8 + (unsigned)(cq & 7);
                *reinterpret_cast<u16x4*>(o1 + off) = ov;
            }
        }
    } else {
        float* o1 = (float*)outp;
        const int HW = 1 << LHW;
#pragma unroll
        for (int nf = 0; nf < NF; ++nf) {
            const int cq = co_base + nf * 16 + (lhi << 2);
            float sc[4], bi[4];
#pragma unroll
            for (int r = 0; r < 4; r++) {
                int c = min(cq + r, COclamp - 1);
                sc[r] = g[c] * BNS; bi[r] = bia[c];
            }
#pragma unroll
            for (int mf = 0; mf < MF; ++mf) {
                int px = px0 + mf * 16 + l15;
                int b = px >> LHW, phw = px & (HW - 1);
#pragma unroll
                for (int r = 0; r < 4; r++) {
                    float v = fmaf(acc[nf][mf][r], sc[r], bi[r]);
                    if (relu) v = fmaxf(v, 0.f);
                    o1[((size_t)(b * COT + cq + r)) * HW + phw] = v;
                }
            }
        }
    }
}

// ============================================================================
// 2x bilinear resize (align-corners linspace), T16 bf16, C=64, 64x64 -> 128x128
// ============================================================================
__global__ __launch_bounds__(256)
void resize2x_t16(const ushort_t* __restrict__ in, ushort_t* __restrict__ out)
{
    int t = blockIdx.x * 256 + threadIdx.x;
    int cg = t & 7;
    int opx = t >> 3;
    int xo = opx & 127;
    int rest = opx >> 7;
    int yo = rest & 127;
    int b  = rest >> 7;
    float fy = (float)yo * 63.f / 127.f;
    float fx = (float)xo * 63.f / 127.f;
    int y0 = (int)fy, x0 = (int)fx;
    float wy = fy - (float)y0, wx = fx - (float)x0;
    int y1 = min(y0 + 1, 63), x1 = min(x0 + 1, 63);
    int qb = b * 4096;
#define RD(Y, X) (*reinterpret_cast<const bf16x8*>(in + \
    (unsigned)(((qb + (Y) * 64 + (X)) >> 4) * 1024) + cg * 128 + ((qb + (Y) * 64 + (X)) & 15) * 8))
    bf16x8 v00 = RD(y0, x0), v01 = RD(y0, x1), v10 = RD(y1, x0), v11 = RD(y1, x1);
#undef RD
    u16x8 o;
#pragma unroll
    for (int k = 0; k < 8; k++) {
        float l = b2f((ushort_t)v00[k]) * (1.f - wy) + b2f((ushort_t)v10[k]) * wy;
        float r = b2f((ushort_t)v01[k]) * (1.f - wy) + b2f((ushort_t)v11[k]) * wy;
        o[k] = f2b(l * (1.f - wx) + r * wx);
    }
    *reinterpret_cast<u16x8*>(out + (unsigned)(opx >> 4) * 1024 + cg * 128 + (opx & 15) * 8) = o;
}

// ============================================================================
// softmax over 25 channels, T16 (CO tile 32), in place
// ============================================================================
__global__ __launch_bounds__(256)
void softmax25(ushort_t* __restrict__ wm, int npx)
{
    int px = blockIdx.x * 256 + threadIdx.x;
    if (px >= npx) return;
    ushort_t* p = wm + (unsigned)(px >> 4) * 512 + (px & 15) * 8;
    u16x8 r0 = *reinterpret_cast<u16x8*>(p);
    u16x8 r1 = *reinterpret_cast<u16x8*>(p + 128);
    u16x8 r2 = *reinterpret_cast<u16x8*>(p + 256);
    float v[25];
#pragma unroll
    for (int k = 0; k < 8; k++) v[k]      = b2f(r0[k]);
#pragma unroll
    for (int k = 0; k < 8; k++) v[8 + k]  = b2f(r1[k]);
#pragma unroll
    for (int k = 0; k < 8; k++) v[16 + k] = b2f(r2[k]);
    v[24] = b2f(p[384]);
    float m = v[0];
#pragma unroll
    for (int c = 1; c < 25; c++) m = fmaxf(m, v[c]);
    float s = 0.f;
#pragma unroll
    for (int c = 0; c < 25; c++) { v[c] = __expf(v[c] - m); s += v[c]; }
    float inv = 1.f / s;
    u16x8 o0, o1, o2;
#pragma unroll
    for (int k = 0; k < 8; k++) o0[k] = f2b(v[k] * inv);
#pragma unroll
    for (int k = 0; k < 8; k++) o1[k] = f2b(v[8 + k] * inv);
#pragma unroll
    for (int k = 0; k < 8; k++) o2[k] = f2b(v[16 + k] * inv);
    *reinterpret_cast<u16x8*>(p)       = o0;
    *reinterpret_cast<u16x8*>(p + 128) = o1;
    *reinterpret_cast<u16x8*>(p + 256) = o2;
    p[384] = f2b(v[24] * inv);
}

// ============================================================================
// CARAFE combine (T16 bf16, C=64, H=W=128)
// ============================================================================
__global__ __launch_bounds__(256)
void carafe25(const ushort_t* __restrict__ wm, const ushort_t* __restrict__ xu,
              ushort_t* __restrict__ out)
{
    int t = blockIdx.x * 256 + threadIdx.x;
    int cg = t & 7;
    int px = t >> 3;
    int x = px & 127;
    int y = (px >> 7) & 127;
    const ushort_t* wp = wm + (unsigned)(px >> 4) * 512 + (px & 15) * 8;
    u16x8 r0 = *reinterpret_cast<const u16x8*>(wp);
    u16x8 r1 = *reinterpret_cast<const u16x8*>(wp + 128);
    u16x8 r2 = *reinterpret_cast<const u16x8*>(wp + 256);
    float v[25];
#pragma unroll
    for (int k = 0; k < 8; k++) v[k]      = b2f(r0[k]);
#pragma unroll
    for (int k = 0; k < 8; k++) v[8 + k]  = b2f(r1[k]);
#pragma unroll
    for (int k = 0; k < 8; k++) v[16 + k] = b2f(r2[k]);
    v[24] = b2f(wp[384]);

    float acc[8];
#pragma unroll
    for (int k = 0; k < 8; k++) acc[k] = 0.f;
#pragma unroll
    for (int i = 0; i < 5; i++) {
        int yy = y + 2 * i - 4;
#pragma unroll
        for (int j = 0; j < 5; j++) {
            int xx = x + 2 * j - 4;
            if (yy >= 0 && yy < 128 && xx >= 0 && xx < 128) {
                int q = px + (2 * i - 4) * 128 + (2 * j - 4);
                bf16x8 xv = *reinterpret_cast<const bf16x8*>(
                    xu + (unsigned)(q >> 4) * 1024 + cg * 128 + (q & 15) * 8);
                float wv = v[i * 5 + j];
#pragma unroll
                for (int k = 0; k < 8; k++)
                    acc[k] = fmaf(wv, b2f((ushort_t)xv[k]), acc[k]);
            }
        }
    }
    u16x8 o;
#pragma unroll
    for (int k = 0; k < 8; k++) o[k] = f2b(acc[k]);
    *reinterpret_cast<u16x8*>(out + (unsigned)(px >> 4) * 1024 + cg * 128 + (px & 15) * 8) = o;
}

// ============================================================================
extern "C" void kernel_launch(void* const* d_in, const int* in_sizes, int n_in,
                              void* d_out, int out_size, void* d_ws, size_t ws_size,
                              hipStream_t stream)
{
    const float* x_h      = (const float*)d_in[0];
    const float* x_l      = (const float*)d_in[1];
    const float* w_reduce = (const float*)d_in[2];
    const float* g_reduce = (const float*)d_in[3];
    const float* b_reduce = (const float*)d_in[4];
    const float* w1       = (const float*)d_in[5];
    const float* g1       = (const float*)d_in[6];
    const float* b1       = (const float*)d_in[7];
    const float* w2       = (const float*)d_in[8];
    const float* g2       = (const float*)d_in[9];
    const float* b2       = (const float*)d_in[10];
    const float* w_enc    = (const float*)d_in[11];
    const float* g_enc    = (const float*)d_in[12];
    const float* b_enc    = (const float*)d_in[13];
    const float* w_out1   = (const float*)d_in[14];
    const float* g_out1   = (const float*)d_in[15];
    const float* b_out1   = (const float*)d_in[16];
    const float* w_out2   = (const float*)d_in[17];
    const float* g_out2   = (const float*)d_in[18];
    const float* b_out2   = (const float*)d_in[19];

    ushort_t* ws0 = (ushort_t*)d_ws;

    const unsigned oXHC = OFF_R1;   // (16384, 256) T16
    const unsigned oC1  = OFF_R2;   // (16384, 64)
    const unsigned oXR  = OFF_R3;   // (16384, 64)
    const unsigned oX1  = OFF_R4;   // (65536, 64)
    const unsigned oXLC = OFF_R5;   // (65536, 128)
    const unsigned oX2  = OFF_R1;   // (65536, 64)   xh_c dead
    const unsigned oWM  = OFF_R6;   // (65536, 32)
    const unsigned oXU  = OFF_R4;   // (65536, 64)   x1 dead
    const unsigned oXB  = OFF_R1;   // (65536, 64)   x2 dead
    const unsigned oY1  = OFF_R4;   // (65536, 128)  contiguous R4..R5

    // 0) weights -> bf16 [kt][co][32] + zero page
    prep_weights<<<1872, 256, 0, stream>>>(w_reduce, w1, w2, w_enc, w_out1, w_out2, ws0);
    // 1) x_h -> T16 bf16
    nchw2t16<<<64, 256, 0, stream>>>(x_h, ws0 + oXHC, 256, 12, 16384);
    // 2) c1 = cbr1x1(xh_c, w1): M=16384 K=256 CO=64
    conv_mfma<1, 1, 2, 256, 0, 64, 1, 0><<<dim3(256, 2), 256, 0, stream>>>(
        ws0, oXHC, 0u, E_BW1, g1, b1, 64, ws0 + oC1, 6, 64, 12, 1);
    // 3) xr = cbr3x3(xh_c, w_reduce): M=16384 K=2304 CO=64
    conv_mfma<9, 1, 2, 256, 0, 64, 1, 0><<<dim3(256, 2), 256, 0, stream>>>(
        ws0, oXHC, 0u, E_BWR, g_reduce, b_reduce, 64, ws0 + oXR, 6, 64, 12, 1);
    // 4) x1 = resize2x(c1)
    resize2x_t16<<<2048, 256, 0, stream>>>(ws0 + oC1, ws0 + oX1);
    // 5) x_l -> T16 bf16
    nchw2t16<<<256, 256, 0, stream>>>(x_l, ws0 + oXLC, 128, 14, 65536);
    // 6) x2 = cbr1x1(xl_c, w2): M=65536 K=128 CO=64
    conv_mfma<1, 2, 2, 128, 0, 64, 1, 0><<<dim3(512, 2), 256, 0, stream>>>(
        ws0, oXLC, 0u, E_BW2, g2, b2, 64, ws0 + oX2, 7, 128, 14, 1);
    // 7) wm = conv3x3(concat(x1,x2), w_enc), no relu: CO=32 (25 real)
    conv_mfma<9, 1, 2, 64, 64, 32, 0, 0><<<dim3(1024, 1), 256, 0, stream>>>(
        ws0, oX1, oX2, E_BWE, g_enc, b_enc, 25, ws0 + oWM, 7, 128, 14, 0);
    // 8) softmax over 25 mask channels (in place)
    softmax25<<<256, 256, 0, stream>>>(ws0 + oWM, 65536);
    // 9) xu = resize2x(xr)
    resize2x_t16<<<2048, 256, 0, stream>>>(ws0 + oXR, ws0 + oXU);
    // 10) X = carafe(wm, xu)
    carafe25<<<2048, 256, 0, stream>>>(ws0 + oWM, ws0 + oXU, ws0 + oXB);
    // 11) y1 = cbr3x3(concat(X, xl_c), w_out1): CO=128
    conv_mfma<9, 2, 4, 64, 128, 128, 1, 0><<<dim3(512, 2), 256, 0, stream>>>(
        ws0, oXB, oXLC, E_BWO1, g_out1, b_out1, 128, ws0 + oY1, 7, 128, 14, 1);
    // 12) out = cbr1x1(y1, w_out2) -> d_out NCHW f32
    conv_mfma<1, 2, 4, 128, 0, 128, 1, 1><<<dim3(512, 2), 256, 0, stream>>>(
        ws0, oY1, 0u, E_BWO2, g_out2, b_out2, 128, d_out, 7, 128, 14, 1);
}

// Round 5
// 192.342 us; speedup vs baseline: 8.6205x; 1.1135x over previous
//
#include <hip/hip_runtime.h>
#include <math.h>

#define BNS 0.99999500003749981f  // 1/sqrt(1+1e-5)

typedef short          bf16x8  __attribute__((ext_vector_type(8)));
typedef float          f32x4   __attribute__((ext_vector_type(4)));
typedef unsigned short u16x8   __attribute__((ext_vector_type(8)));
typedef unsigned short u16x4   __attribute__((ext_vector_type(4)));
typedef unsigned short ushort_t;

__device__ inline ushort_t f2b(float f) {
    union { float f; unsigned int u; } x; x.f = f;
    unsigned int u = x.u;
    unsigned int r = (u + 0x7FFFu + ((u >> 16) & 1u)) >> 16;   // RNE
    return (ushort_t)r;
}
__device__ inline float b2f(ushort_t s) {
    union { unsigned int u; float f; } x; x.u = ((unsigned int)s) << 16;
    return x.f;
}

// async global->LDS, 16B per lane; LDS dest is wave-uniform base (+lane*16 by HW)
__device__ inline void glds16(const ushort_t* gp, void* lp) {
    __builtin_amdgcn_global_load_lds(
        (const __attribute__((address_space(1))) unsigned int*)gp,
        (__attribute__((address_space(3))) unsigned int*)lp, 16, 0, 0);
}

// ---------------- workspace element offsets (ushort units) ----------------
#define E_BWR   0u
#define E_BW1   147456u
#define E_BW2   163840u
#define E_BWE   172032u
#define E_BWO1  208896u
#define E_BWO2  430080u
#define E_ZP    446464u      // 64KB zero page (32768 el)
#define OFF_R1  524288u      // 8MB region   (byte 1048576)
#define OFF_R4  4718592u     // 8MB          (byte 9437184)
#define OFF_R2  8912896u     // 2MB          (byte 17825792)
#define OFF_R3  9961472u     // 2MB          (byte 19922944)
#define OFF_R6  11010048u    // 4MB          (byte 22020096)
#define OFF_R5  13107200u    // 16MB         (byte 26214400) end byte 42991616

// T16 activation layout: element (px, ci) of a CI-channel tensor lives at
//   (px>>4)*(CI*16) + (ci>>3)*128 + (px&15)*8 + (ci&7)
// -> a (16px x 32ci) staging chunk is 1KB contiguous.

// ============================================================================
// Weight prep: OIHW f32 -> [kt][ci_oct(4)][co][8] bf16.  kt = tap*KCT + j
// (j runs A-source 32ci chunks then B-source).  A (BN co x 32ci) K-step tile
// is contiguous; ds_read W-fragments are 16B-per-co -> conflict-free.
// ============================================================================
__device__ inline void wseg3(int idx, const float* src, ushort_t* dst,
                             int TAPS, int COT, int CIT, int CO_real) {
    int kt  = idx / (COT * 32);
    int r   = idx - kt * (COT * 32);
    int q   = r / (COT * 8);
    int r2  = r - q * (COT * 8);
    int co  = r2 >> 3;
    int e   = r2 & 7;
    int KCT = CIT >> 5;
    int tap = kt / KCT, j = kt - tap * KCT;
    int ci  = j * 32 + q * 8 + e;
    float v = (co < CO_real) ? src[((size_t)co * CIT + ci) * TAPS + tap] : 0.f;
    dst[idx] = f2b(v);
}

__global__ __launch_bounds__(256)
void prep_weights(const float* wr, const float* w1, const float* w2,
                  const float* we, const float* wo1, const float* wo2,
                  ushort_t* ws0)
{
    int idx = blockIdx.x * 256 + threadIdx.x;
    const int n0 = 9*64*256;    // reduce   147456
    const int n1 = 64*256;      // w1        16384
    const int n2 = 64*128;      // w2         8192
    const int n3 = 9*32*128;    // enc       36864
    const int n4 = 9*128*192;   // out1     221184
    const int n5 = 128*128;     // out2      16384
    if (idx < n0) { wseg3(idx, wr,  ws0 + E_BWR,  9, 64, 256, 64);  return; } idx -= n0;
    if (idx < n1) { wseg3(idx, w1,  ws0 + E_BW1,  1, 64, 256, 64);  return; } idx -= n1;
    if (idx < n2) { wseg3(idx, w2,  ws0 + E_BW2,  1, 64, 128, 64);  return; } idx -= n2;
    if (idx < n3) { wseg3(idx, we,  ws0 + E_BWE,  9, 32, 128, 25);  return; } idx -= n3;
    if (idx < n4) { wseg3(idx, wo1, ws0 + E_BWO1, 9, 128, 192, 128); return; } idx -= n4;
    if (idx < n5) { wseg3(idx, wo2, ws0 + E_BWO2, 1, 128, 128, 128); return; } idx -= n5;
    if (idx < 32768) ws0[E_ZP + idx] = 0;   // zero page
}

// ============================================================================
// NCHW f32 -> T16 bf16
// ============================================================================
__global__ __launch_bounds__(256)
void nchw2t16(const float* __restrict__ in, ushort_t* __restrict__ out,
              int C, int LHW, int npx)
{
    int px = blockIdx.x * 256 + threadIdx.x;
    if (px >= npx) return;
    int HW = 1 << LHW;
    int b = px >> LHW, phw = px & (HW - 1);
    const float* src = in + (size_t)b * C * HW + phw;
    unsigned base = (unsigned)(px >> 4) * (C * 16) + (unsigned)(px & 15) * 8;
    for (int c0 = 0; c0 < C; c0 += 8) {
        u16x8 o;
#pragma unroll
        for (int j = 0; j < 8; j++) o[j] = f2b(src[(size_t)(c0 + j) * HW]);
        *reinterpret_cast<u16x8*>(out + base + (c0 >> 3) * 128) = o;
    }
}

// ============================================================================
// LDS-staged implicit-GEMM conv (m97 structure).
// Block = one image row (BM=W px) x BN co.  4 waves: (w&1)->px half,
// (w>>1)->co half.  Per K-step (one tap, one 32ci chunk):
//   sync; global_load_lds act row(+dy) chunk + weight tile; sync;
//   ds_read_b128 fragments; MFMA.
// Borders: dy -> whole-row redirect to global zero page (uniform);
//          dx -> per-lane ds_read address select to a 16B LDS zero slot.
// ============================================================================
template<int TAPS, int BM, int CIA, int CIB, int COT, int BN, int EPI>
__global__ __launch_bounds__(256)
void conv_lds(const ushort_t* __restrict__ ws0,
              unsigned offA, unsigned offB, unsigned offW,
              const float* __restrict__ g, const float* __restrict__ bia,
              int COclamp, void* __restrict__ outp,
              int H, int LHW, int relu)
{
    constexpr int KCA = CIA / 32, KCB = CIB / 32;
    constexpr int MF = BM / 32, NF = BN / 32;      // per-wave fragments
    constexpr int ACHUNK = BM / 16;                // 1KB act chunks
    constexpr int WUNIT  = BN / 16;                // 1KB weight units
    constexpr int WOFF = BM * 64;
    constexpr int ZSLOT = BM * 64 + BN * 64;
    constexpr int LBN3 = (BN == 128) ? 10 : (BN == 64) ? 9 : 8;  // log2(BN*8)
    __shared__ char lds[BM * 64 + BN * 64 + 16];

    // bijective XCD-chunked swizzle on x (keeps adjacent rows on one XCD L2)
    const unsigned nwg = gridDim.x, o = blockIdx.x;
    const unsigned qq = nwg >> 3, r8 = nwg & 7, xc = o & 7, k0 = o >> 3;
    const unsigned bx = (xc < r8 ? xc * (qq + 1) : r8 * (qq + 1) + (xc - r8) * qq) + k0;
    const int co_blk = blockIdx.y * BN;

    const int tid = threadIdx.x, w = tid >> 6, lane = tid & 63;
    const int l15 = lane & 15, lhi = lane >> 4;
    const int wpx = (w & 1) * (BM / 2), cw0 = (w >> 1) * (BN / 2);
    const int yb = (int)(bx & (unsigned)(H - 1));      // BM == W: block = row yb
    const unsigned pxc0 = bx * ACHUNK;

    if (tid < 4) *(unsigned*)(lds + ZSLOT + tid * 4) = 0u;

    int wAddr[NF];
#pragma unroll
    for (int nf = 0; nf < NF; ++nf)
        wAddr[nf] = WOFF + (lhi * BN + cw0 + nf * 16 + l15) * 16;

    f32x4 acc[NF][MF];
#pragma unroll
    for (int nf = 0; nf < NF; ++nf)
#pragma unroll
        for (int mf = 0; mf < MF; ++mf)
            acc[nf][mf] = (f32x4){0.f, 0.f, 0.f, 0.f};

    unsigned wBase = offW;

    auto do_steps = [&](unsigned srcOff, int CI16, int KC, bool rowv,
                        const int (&aA)[MF]) {
#pragma unroll 1
        for (int j = 0; j < KC; ++j) {
            __syncthreads();                      // prev reads done
            // ---- stage act (BM x 32ci)
#pragma unroll
            for (int i = 0; i < ACHUNK / 4; ++i) {
                int u = i * 4 + w;
                unsigned s = rowv ? (srcOff + (unsigned)u * CI16 + (unsigned)j * 512 + lane * 8)
                                  : (E_ZP + lane * 8);
                glds16(ws0 + s, lds + u * 1024);
            }
            // ---- stage weights (BN x 32ci), layout [q][co][8]
#pragma unroll
            for (int i = 0; i < (WUNIT + 3) / 4; ++i) {
                int u = i * 4 + w;
                if (WUNIT >= 4 || w < WUNIT) {
                    int el  = u * 512 + lane * 8;
                    int q   = el >> LBN3;
                    int col = (el & ((1 << LBN3) - 1)) >> 3;
                    glds16(ws0 + wBase + q * (COT * 8) + (co_blk + col) * 8,
                           lds + WOFF + u * 1024);
                }
            }
            __syncthreads();                      // staged data visible
            // ---- fragments + MFMA
            bf16x8 af[MF], wf[NF];
#pragma unroll
            for (int mf = 0; mf < MF; ++mf)
                af[mf] = *reinterpret_cast<const bf16x8*>(lds + aA[mf]);
#pragma unroll
            for (int nf = 0; nf < NF; ++nf)
                wf[nf] = *reinterpret_cast<const bf16x8*>(lds + wAddr[nf]);
#pragma unroll
            for (int nf = 0; nf < NF; ++nf)
#pragma unroll
                for (int mf = 0; mf < MF; ++mf)
                    acc[nf][mf] = __builtin_amdgcn_mfma_f32_16x16x32_bf16(
                        wf[nf], af[mf], acc[nf][mf], 0, 0, 0);
            wBase += COT * 32;
        }
    };

#pragma unroll
    for (int tap = 0; tap < TAPS; ++tap) {
        const int dy = (TAPS == 9) ? tap / 3 - 1 : 0;
        const int dx = (TAPS == 9) ? tap % 3 - 1 : 0;
        const int yy = yb + dy;
        const bool rowv = (TAPS == 1) || ((yy >= 0) && (yy < H));
        int aA[MF];
#pragma unroll
        for (int mf = 0; mf < MF; ++mf) {
            int pr = wpx + mf * 16 + l15 + dx;
            bool ok = (TAPS == 1) || ((pr >= 0) && (pr < BM));
            aA[mf] = ok ? (((pr >> 4) << 10) + (lhi << 8) + ((pr & 15) << 4)) : ZSLOT;
        }
        unsigned srcA = offA + (unsigned)((int)pxc0 + dy * ACHUNK) * (unsigned)(CIA * 16);
        do_steps(srcA, CIA * 16, KCA, rowv, aA);
        if constexpr (CIB > 0) {
            unsigned srcB = offB + (unsigned)((int)pxc0 + dy * ACHUNK) * (unsigned)(CIB * 16);
            do_steps(srcB, CIB * 16, KCB, rowv, aA);
        }
    }

    // ---------------- epilogue ----------------
    if (EPI == 0) {
        ushort_t* o1 = (ushort_t*)outp;
#pragma unroll
        for (int nf = 0; nf < NF; ++nf) {
            const int cg = co_blk + cw0 + nf * 16 + (lhi << 2);  // first of 4 co
            float sc[4], bi[4];
#pragma unroll
            for (int r = 0; r < 4; r++) {
                int c = min(cg + r, COclamp - 1);
                sc[r] = g[c] * BNS; bi[r] = bia[c];
            }
#pragma unroll
            for (int mf = 0; mf < MF; ++mf) {
                f32x4 a = acc[nf][mf];
                u16x4 ov;
#pragma unroll
                for (int r = 0; r < 4; r++) {
                    float v = fmaf(a[r], sc[r], bi[r]);
                    if (relu) v = fmaxf(v, 0.f);
                    ov[r] = f2b(v);
                }
                int px = (int)bx * BM + wpx + mf * 16 + l15;
                unsigned off = (unsigned)(px >> 4) * (COT * 16)
                             + (unsigned)(cg >> 3) * 128
                             + (unsigned)(px & 15) * 8 + (unsigned)(cg & 7);
                *reinterpret_cast<u16x4*>(o1 + off) = ov;
            }
        }
    } else {
        float* o1 = (float*)outp;
        const int HW = 1 << LHW;
#pragma unroll
        for (int nf = 0; nf < NF; ++nf) {
            const int cg = co_blk + cw0 + nf * 16 + (lhi << 2);
            float sc[4], bi[4];
#pragma unroll
            for (int r = 0; r < 4; r++) {
                int c = min(cg + r, COclamp - 1);
                sc[r] = g[c] * BNS; bi[r] = bia[c];
            }
#pragma unroll
            for (int mf = 0; mf < MF; ++mf) {
                int px = (int)bx * BM + wpx + mf * 16 + l15;
                int b = px >> LHW, phw = px & (HW - 1);
#pragma unroll
                for (int r = 0; r < 4; r++) {
                    float v = fmaf(acc[nf][mf][r], sc[r], bi[r]);
                    if (relu) v = fmaxf(v, 0.f);
                    o1[((size_t)(b * COT + cg + r)) * HW + phw] = v;
                }
            }
        }
    }
}

// ============================================================================
// 2x bilinear resize (align-corners linspace), T16 bf16, C=64, 64x64 -> 128x128
// ============================================================================
__global__ __launch_bounds__(256)
void resize2x_t16(const ushort_t* __restrict__ in, ushort_t* __restrict__ out)
{
    int t = blockIdx.x * 256 + threadIdx.x;
    int cg = t & 7;
    int opx = t >> 3;
    int xo = opx & 127;
    int rest = opx >> 7;
    int yo = rest & 127;
    int b  = rest >> 7;
    float fy = (float)yo * 63.f / 127.f;
    float fx = (float)xo * 63.f / 127.f;
    int y0 = (int)fy, x0 = (int)fx;
    float wy = fy - (float)y0, wx = fx - (float)x0;
    int y1 = min(y0 + 1, 63), x1 = min(x0 + 1, 63);
    int qb = b * 4096;
#define RD(Y, X) (*reinterpret_cast<const bf16x8*>(in + \
    (unsigned)(((qb + (Y) * 64 + (X)) >> 4) * 1024) + cg * 128 + ((qb + (Y) * 64 + (X)) & 15) * 8))
    bf16x8 v00 = RD(y0, x0), v01 = RD(y0, x1), v10 = RD(y1, x0), v11 = RD(y1, x1);
#undef RD
    u16x8 o;
#pragma unroll
    for (int k = 0; k < 8; k++) {
        float l = b2f((ushort_t)v00[k]) * (1.f - wy) + b2f((ushort_t)v10[k]) * wy;
        float r = b2f((ushort_t)v01[k]) * (1.f - wy) + b2f((ushort_t)v11[k]) * wy;
        o[k] = f2b(l * (1.f - wx) + r * wx);
    }
    *reinterpret_cast<u16x8*>(out + (unsigned)(opx >> 4) * 1024 + cg * 128 + (opx & 15) * 8) = o;
}

// ============================================================================
// softmax over 25 channels, T16 (CO tile 32), in place
// ============================================================================
__global__ __launch_bounds__(256)
void softmax25(ushort_t* __restrict__ wm, int npx)
{
    int px = blockIdx.x * 256 + threadIdx.x;
    if (px >= npx) return;
    ushort_t* p = wm + (unsigned)(px >> 4) * 512 + (px & 15) * 8;
    u16x8 r0 = *reinterpret_cast<u16x8*>(p);
    u16x8 r1 = *reinterpret_cast<u16x8*>(p + 128);
    u16x8 r2 = *reinterpret_cast<u16x8*>(p + 256);
    float v[25];
#pragma unroll
    for (int k = 0; k < 8; k++) v[k]      = b2f(r0[k]);
#pragma unroll
    for (int k = 0; k < 8; k++) v[8 + k]  = b2f(r1[k]);
#pragma unroll
    for (int k = 0; k < 8; k++) v[16 + k] = b2f(r2[k]);
    v[24] = b2f(p[384]);
    float m = v[0];
#pragma unroll
    for (int c = 1; c < 25; c++) m = fmaxf(m, v[c]);
    float s = 0.f;
#pragma unroll
    for (int c = 0; c < 25; c++) { v[c] = __expf(v[c] - m); s += v[c]; }
    float inv = 1.f / s;
    u16x8 o0, o1, o2;
#pragma unroll
    for (int k = 0; k < 8; k++) o0[k] = f2b(v[k] * inv);
#pragma unroll
    for (int k = 0; k < 8; k++) o1[k] = f2b(v[8 + k] * inv);
#pragma unroll
    for (int k = 0; k < 8; k++) o2[k] = f2b(v[16 + k] * inv);
    *reinterpret_cast<u16x8*>(p)       = o0;
    *reinterpret_cast<u16x8*>(p + 128) = o1;
    *reinterpret_cast<u16x8*>(p + 256) = o2;
    p[384] = f2b(v[24] * inv);
}

// ============================================================================
// CARAFE combine (T16 bf16, C=64, H=W=128)
// ============================================================================
__global__ __launch_bounds__(256)
void carafe25(const ushort_t* __restrict__ wm, const ushort_t* __restrict__ xu,
              ushort_t* __restrict__ out)
{
    int t = blockIdx.x * 256 + threadIdx.x;
    int cg = t & 7;
    int px = t >> 3;
    int x = px & 127;
    int y = (px >> 7) & 127;
    const ushort_t* wp = wm + (unsigned)(px >> 4) * 512 + (px & 15) * 8;
    u16x8 r0 = *reinterpret_cast<const u16x8*>(wp);
    u16x8 r1 = *reinterpret_cast<const u16x8*>(wp + 128);
    u16x8 r2 = *reinterpret_cast<const u16x8*>(wp + 256);
    float v[25];
#pragma unroll
    for (int k = 0; k < 8; k++) v[k]      = b2f(r0[k]);
#pragma unroll
    for (int k = 0; k < 8; k++) v[8 + k]  = b2f(r1[k]);
#pragma unroll
    for (int k = 0; k < 8; k++) v[16 + k] = b2f(r2[k]);
    v[24] = b2f(wp[384]);

    float acc[8];
#pragma unroll
    for (int k = 0; k < 8; k++) acc[k] = 0.f;
#pragma unroll
    for (int i = 0; i < 5; i++) {
        int yy = y + 2 * i - 4;
#pragma unroll
        for (int j = 0; j < 5; j++) {
            int xx = x + 2 * j - 4;
            if (yy >= 0 && yy < 128 && xx >= 0 && xx < 128) {
                int q = px + (2 * i - 4) * 128 + (2 * j - 4);
                bf16x8 xv = *reinterpret_cast<const bf16x8*>(
                    xu + (unsigned)(q >> 4) * 1024 + cg * 128 + (q & 15) * 8);
                float wv = v[i * 5 + j];
#pragma unroll
                for (int k = 0; k < 8; k++)
                    acc[k] = fmaf(wv, b2f((ushort_t)xv[k]), acc[k]);
            }
        }
    }
    u16x8 o;
#pragma unroll
    for (int k = 0; k < 8; k++) o[k] = f2b(acc[k]);
    *reinterpret_cast<u16x8*>(out + (unsigned)(px >> 4) * 1024 + cg * 128 + (px & 15) * 8) = o;
}

// ============================================================================
extern "C" void kernel_launch(void* const* d_in, const int* in_sizes, int n_in,
                              void* d_out, int out_size, void* d_ws, size_t ws_size,
                              hipStream_t stream)
{
    const float* x_h      = (const float*)d_in[0];
    const float* x_l      = (const float*)d_in[1];
    const float* w_reduce = (const float*)d_in[2];
    const float* g_reduce = (const float*)d_in[3];
    const float* b_reduce = (const float*)d_in[4];
    const float* w1       = (const float*)d_in[5];
    const float* g1       = (const float*)d_in[6];
    const float* b1       = (const float*)d_in[7];
    const float* w2       = (const float*)d_in[8];
    const float* g2       = (const float*)d_in[9];
    const float* b2       = (const float*)d_in[10];
    const float* w_enc    = (const float*)d_in[11];
    const float* g_enc    = (const float*)d_in[12];
    const float* b_enc    = (const float*)d_in[13];
    const float* w_out1   = (const float*)d_in[14];
    const float* g_out1   = (const float*)d_in[15];
    const float* b_out1   = (const float*)d_in[16];
    const float* w_out2   = (const float*)d_in[17];
    const float* g_out2   = (const float*)d_in[18];
    const float* b_out2   = (const float*)d_in[19];

    ushort_t* ws0 = (ushort_t*)d_ws;

    const unsigned oXHC = OFF_R1;   // (16384, 256) T16
    const unsigned oC1  = OFF_R2;   // (16384, 64)
    const unsigned oXR  = OFF_R3;   // (16384, 64)
    const unsigned oX1  = OFF_R4;   // (65536, 64)
    const unsigned oXLC = OFF_R5;   // (65536, 128)
    const unsigned oX2  = OFF_R1;   // (65536, 64)   xh_c dead
    const unsigned oWM  = OFF_R6;   // (65536, 32)
    const unsigned oXU  = OFF_R4;   // (65536, 64)   x1 dead
    const unsigned oXB  = OFF_R1;   // (65536, 64)   x2 dead
    const unsigned oY1  = OFF_R4;   // (65536, 128)

    // 0) weights -> bf16 [kt][ci_oct][co][8] + zero page
    prep_weights<<<1872, 256, 0, stream>>>(w_reduce, w1, w2, w_enc, w_out1, w_out2, ws0);
    // 1) x_h -> T16 bf16
    nchw2t16<<<64, 256, 0, stream>>>(x_h, ws0 + oXHC, 256, 12, 16384);
    // 2) c1 = cbr1x1(xh_c, w1): M=16384 K=256 CO=64
    conv_lds<1, 64, 256, 0, 64, 32, 0><<<dim3(256, 2), 256, 0, stream>>>(
        ws0, oXHC, 0u, E_BW1, g1, b1, 64, ws0 + oC1, 64, 12, 1);
    // 3) xr = cbr3x3(xh_c, w_reduce): M=16384 K=2304 CO=64
    conv_lds<9, 64, 256, 0, 64, 32, 0><<<dim3(256, 2), 256, 0, stream>>>(
        ws0, oXHC, 0u, E_BWR, g_reduce, b_reduce, 64, ws0 + oXR, 64, 12, 1);
    // 4) x1 = resize2x(c1)
    resize2x_t16<<<2048, 256, 0, stream>>>(ws0 + oC1, ws0 + oX1);
    // 5) x_l -> T16 bf16
    nchw2t16<<<256, 256, 0, stream>>>(x_l, ws0 + oXLC, 128, 14, 65536);
    // 6) x2 = cbr1x1(xl_c, w2): M=65536 K=128 CO=64
    conv_lds<1, 128, 128, 0, 64, 64, 0><<<dim3(512, 1), 256, 0, stream>>>(
        ws0, oXLC, 0u, E_BW2, g2, b2, 64, ws0 + oX2, 128, 14, 1);
    // 7) wm = conv3x3(concat(x1,x2), w_enc), no relu: CO=32 (25 real)
    conv_lds<9, 128, 64, 64, 32, 32, 0><<<dim3(512, 1), 256, 0, stream>>>(
        ws0, oX1, oX2, E_BWE, g_enc, b_enc, 25, ws0 + oWM, 128, 14, 0);
    // 8) softmax over 25 mask channels (in place)
    softmax25<<<256, 256, 0, stream>>>(ws0 + oWM, 65536);
    // 9) xu = resize2x(xr)
    resize2x_t16<<<2048, 256, 0, stream>>>(ws0 + oXR, ws0 + oXU);
    // 10) X = carafe(wm, xu)
    carafe25<<<2048, 256, 0, stream>>>(ws0 + oWM, ws0 + oXU, ws0 + oXB);
    // 11) y1 = cbr3x3(concat(X, xl_c), w_out1): CO=128
    conv_lds<9, 128, 64, 128, 128, 128, 0><<<dim3(512, 1), 256, 0, stream>>>(
        ws0, oXB, oXLC, E_BWO1, g_out1, b_out1, 128, ws0 + oY1, 128, 14, 1);
    // 12) out = cbr1x1(y1, w_out2) -> d_out NCHW f32
    conv_lds<1, 128, 128, 0, 128, 128, 1><<<dim3(512, 1), 256, 0, stream>>>(
        ws0, oY1, 0u, E_BWO2, g_out2, b_out2, 128, d_out, 128, 14, 1);
}